// Round 1
// baseline (1361.753 us; speedup 1.0000x reference)
//
#include <hip/hip_runtime.h>
#include <hip/hip_bf16.h>

#define T_LEN  2048
#define NHEAD  16
#define HDIM   64
#define DMODEL 1024
#define BATCH  2
#define MROWS  4096   // B*T

// ---------------------------------------------------------------------------
// fp32 GEMM: C[M,N] = A[M,K] @ W[K,N]; M=4096, N=K=1024.
// 128x128 block tile, BK=16, 256 threads, 8x8 microtile.
// LDS rows padded to 132 floats: keeps float4 alignment (528B % 16 == 0),
// breaks the 4-way staging-write conflict down to 2-way (free per m136).
// ---------------------------------------------------------------------------
__global__ __launch_bounds__(256) void ha_gemm_f32(
    const float* __restrict__ A, const float* __restrict__ W,
    float* __restrict__ C) {
  const int N = DMODEL, K = DMODEL;
  __shared__ float As[16][132];   // [k][m] (transposed stage)
  __shared__ float Bs[16][132];   // [k][n]
  const int tid  = threadIdx.x;
  const int row0 = blockIdx.y * 128;
  const int n0   = blockIdx.x * 128;
  const int ty = tid >> 4, tx = tid & 15;

  float acc[8][8];
  #pragma unroll
  for (int i = 0; i < 8; ++i)
    #pragma unroll
    for (int j = 0; j < 8; ++j) acc[i][j] = 0.f;

  for (int k0 = 0; k0 < K; k0 += 16) {
    float4 av[2], wv[2];
    #pragma unroll
    for (int r = 0; r < 2; ++r) {
      const int id = tid + 256 * r;
      const int m = id >> 2, kg = id & 3;           // A: 128 rows x 4 float4-of-k
      av[r] = *(const float4*)(A + (size_t)(row0 + m) * K + k0 + kg * 4);
      const int kk = id >> 5, ng = id & 31;         // B: 16 k-rows x 32 float4-of-n
      wv[r] = *(const float4*)(W + (size_t)(k0 + kk) * N + n0 + ng * 4);
    }
    __syncthreads();
    #pragma unroll
    for (int r = 0; r < 2; ++r) {
      const int id = tid + 256 * r;
      const int m = id >> 2, kg = id & 3;
      As[kg * 4 + 0][m] = av[r].x;
      As[kg * 4 + 1][m] = av[r].y;
      As[kg * 4 + 2][m] = av[r].z;
      As[kg * 4 + 3][m] = av[r].w;
      const int kk = id >> 5, ng = id & 31;
      *(float4*)&Bs[kk][ng * 4] = wv[r];
    }
    __syncthreads();
    #pragma unroll
    for (int k = 0; k < 16; ++k) {
      float a8[8], b8[8];
      *(float4*)&a8[0] = *(const float4*)&As[k][ty * 8];
      *(float4*)&a8[4] = *(const float4*)&As[k][ty * 8 + 4];
      *(float4*)&b8[0] = *(const float4*)&Bs[k][tx * 8];
      *(float4*)&b8[4] = *(const float4*)&Bs[k][tx * 8 + 4];
      #pragma unroll
      for (int i = 0; i < 8; ++i)
        #pragma unroll
        for (int j = 0; j < 8; ++j)
          acc[i][j] = fmaf(a8[i], b8[j], acc[i][j]);
    }
  }
  #pragma unroll
  for (int i = 0; i < 8; ++i) {
    float* cp = C + (size_t)(row0 + ty * 8 + i) * N + n0 + tx * 8;
    *(float4*)cp       = make_float4(acc[i][0], acc[i][1], acc[i][2], acc[i][3]);
    *(float4*)(cp + 4) = make_float4(acc[i][4], acc[i][5], acc[i][6], acc[i][7]);
  }
}

// ---------------------------------------------------------------------------
// In-place LayerNorm over each contiguous 64-wide head group.
// One wave per (bt, h) group; wave boundaries align with groups.
// ---------------------------------------------------------------------------
__global__ __launch_bounds__(256) void ha_ln(
    float* __restrict__ Y, const float* __restrict__ gamma,
    const float* __restrict__ beta) {
  const int gtid = blockIdx.x * 256 + threadIdx.x;
  const int wv   = gtid >> 6;          // (bt*16 + h)
  const int lane = gtid & 63;          // d in [0,64)
  const size_t off = (size_t)(wv >> 4) * DMODEL + (size_t)(wv & 15) * HDIM + lane;
  const float v = Y[off];
  float s = v, s2 = v * v;
  #pragma unroll
  for (int m = 32; m >= 1; m >>= 1) {
    s  += __shfl_xor(s, m);
    s2 += __shfl_xor(s2, m);
  }
  const float mean = s * 0.015625f;
  const float var  = s2 * 0.015625f - mean * mean;
  const float rs   = rsqrtf(var + 1e-5f);
  Y[off] = (v - mean) * rs * gamma[lane] + beta[lane];
}

// ---------------------------------------------------------------------------
// Sequential scan per (b,h):  a_excl_t = a_excl_{t-1} + a_{t-1}
//                             S_t      = S_{t-1} + b_t (x) a_excl_t
//                             o_t      = S_t q_t
// Grid = B*H*8 = 256 blocks, 64 threads. Block owns 8 e-rows of S (part).
// Lane (er=lane&7, dp=lane>>3) owns S[e0+er][dp*8 .. dp*8+8) in registers.
// One-step software prefetch of q/a/b hides L1/L2 latency (1 wave/CU).
// o-row reduction over dp via shfl_xor(8,16,32).
// ---------------------------------------------------------------------------
__global__ __launch_bounds__(64) void ha_scan(
    const float* __restrict__ Qn, const float* __restrict__ An,
    const float* __restrict__ Bn, float* __restrict__ On) {
  const int part = blockIdx.x & 7;
  const int bh   = blockIdx.x >> 3;    // b*16 + h
  const int lane = threadIdx.x;
  const int er = lane & 7;
  const int e  = part * 8 + er;
  const int dp = lane >> 3;
  const int d0 = dp * 8;
  const size_t base =
      (size_t)(bh >> 4) * (size_t)T_LEN * DMODEL + (size_t)(bh & 15) * HDIM;
  const float* qp = Qn + base + d0;
  const float* ap = An + base + d0;
  const float* bp = Bn + base + e;

  float S[8], aex[8], apv[8];
  #pragma unroll
  for (int j = 0; j < 8; ++j) { S[j] = 0.f; aex[j] = 0.f; apv[j] = 0.f; }

  float4 q0 = *(const float4*)qp;
  float4 q1 = *(const float4*)(qp + 4);
  float4 a0 = *(const float4*)ap;
  float4 a1 = *(const float4*)(ap + 4);
  float  bc = *bp;

  for (int t = 0; t < T_LEN; ++t) {
    const size_t nofs = (size_t)((t + 1 < T_LEN) ? (t + 1) : t) * DMODEL;
    const float4 nq0 = *(const float4*)(qp + nofs);
    const float4 nq1 = *(const float4*)(qp + nofs + 4);
    const float4 na0 = *(const float4*)(ap + nofs);
    const float4 na1 = *(const float4*)(ap + nofs + 4);
    const float  nb  = *(bp + nofs);

    float qv[8], av[8];
    *(float4*)&qv[0] = q0; *(float4*)&qv[4] = q1;
    *(float4*)&av[0] = a0; *(float4*)&av[4] = a1;

    #pragma unroll
    for (int j = 0; j < 8; ++j) aex[j] += apv[j];
    float po = 0.f;
    #pragma unroll
    for (int j = 0; j < 8; ++j) {
      S[j] = fmaf(bc, aex[j], S[j]);
      po   = fmaf(S[j], qv[j], po);
    }
    po += __shfl_xor(po, 8);
    po += __shfl_xor(po, 16);
    po += __shfl_xor(po, 32);
    if (lane < 8) On[base + (size_t)t * DMODEL + part * 8 + lane] = po;

    #pragma unroll
    for (int j = 0; j < 8; ++j) apv[j] = av[j];
    q0 = nq0; q1 = nq1; a0 = na0; a1 = na1; bc = nb;
  }
}

// ---------------------------------------------------------------------------
extern "C" void kernel_launch(void* const* d_in, const int* in_sizes, int n_in,
                              void* d_out, int out_size, void* d_ws,
                              size_t ws_size, hipStream_t stream) {
  const float* x    = (const float*)d_in[0];
  const float* Wq   = (const float*)d_in[1];
  const float* Wa   = (const float*)d_in[2];
  const float* Wb   = (const float*)d_in[3];
  const float* Wo   = (const float*)d_in[4];
  const float* qg   = (const float*)d_in[5];
  const float* qb   = (const float*)d_in[6];
  const float* ag   = (const float*)d_in[7];
  const float* ab   = (const float*)d_in[8];
  const float* bg   = (const float*)d_in[9];
  const float* bb   = (const float*)d_in[10];
  float* out = (float*)d_out;

  float* ws = (float*)d_ws;
  float* qn = ws;                       // 4096*1024 floats = 16 MB
  float* an = ws + (size_t)MROWS * DMODEL;
  float* bn = ws + (size_t)2 * MROWS * DMODEL;
  float* ob = ws + (size_t)3 * MROWS * DMODEL;   // total 64 MB

  const dim3 ggrid(DMODEL / 128, MROWS / 128);   // (8, 32)
  const int ln_blocks = (MROWS * NHEAD * 64) / 256;  // 16384

  ha_gemm_f32<<<ggrid, 256, 0, stream>>>(x, Wq, qn);
  ha_ln<<<ln_blocks, 256, 0, stream>>>(qn, qg, qb);
  ha_gemm_f32<<<ggrid, 256, 0, stream>>>(x, Wa, an);
  ha_ln<<<ln_blocks, 256, 0, stream>>>(an, ag, ab);
  ha_gemm_f32<<<ggrid, 256, 0, stream>>>(x, Wb, bn);
  ha_ln<<<ln_blocks, 256, 0, stream>>>(bn, bg, bb);
  ha_scan<<<BATCH * NHEAD * 8, 64, 0, stream>>>(qn, an, bn, ob);
  ha_gemm_f32<<<ggrid, 256, 0, stream>>>(ob, Wo, out);
}

// Round 2
// 821.630 us; speedup vs baseline: 1.6574x; 1.6574x over previous
//
#include <hip/hip_runtime.h>
#include <hip/hip_bf16.h>

#define T_LEN  2048
#define NHEAD  16
#define HDIM   64
#define DMODEL 1024
#define BATCH  2
#define MROWS  4096   // B*T
#define L_CHK  64
#define N_CHK  (T_LEN / L_CHK)   // 32
#define BH     (BATCH * NHEAD)   // 32

// ---------------------------------------------------------------------------
// fp32 GEMM: C[M,N] = A[M,K] @ W[K,N]; M=4096, N=K=1024.  (unchanged, known-good)
// ---------------------------------------------------------------------------
__global__ __launch_bounds__(256) void ha_gemm_f32(
    const float* __restrict__ A, const float* __restrict__ W,
    float* __restrict__ C) {
  const int N = DMODEL, K = DMODEL;
  __shared__ float As[16][132];
  __shared__ float Bs[16][132];
  const int tid  = threadIdx.x;
  const int row0 = blockIdx.y * 128;
  const int n0   = blockIdx.x * 128;
  const int ty = tid >> 4, tx = tid & 15;

  float acc[8][8];
  #pragma unroll
  for (int i = 0; i < 8; ++i)
    #pragma unroll
    for (int j = 0; j < 8; ++j) acc[i][j] = 0.f;

  for (int k0 = 0; k0 < K; k0 += 16) {
    float4 av[2], wv[2];
    #pragma unroll
    for (int r = 0; r < 2; ++r) {
      const int id = tid + 256 * r;
      const int m = id >> 2, kg = id & 3;
      av[r] = *(const float4*)(A + (size_t)(row0 + m) * K + k0 + kg * 4);
      const int kk = id >> 5, ng = id & 31;
      wv[r] = *(const float4*)(W + (size_t)(k0 + kk) * N + n0 + ng * 4);
    }
    __syncthreads();
    #pragma unroll
    for (int r = 0; r < 2; ++r) {
      const int id = tid + 256 * r;
      const int m = id >> 2, kg = id & 3;
      As[kg * 4 + 0][m] = av[r].x;
      As[kg * 4 + 1][m] = av[r].y;
      As[kg * 4 + 2][m] = av[r].z;
      As[kg * 4 + 3][m] = av[r].w;
      const int kk = id >> 5, ng = id & 31;
      *(float4*)&Bs[kk][ng * 4] = wv[r];
    }
    __syncthreads();
    #pragma unroll
    for (int k = 0; k < 16; ++k) {
      float a8[8], b8[8];
      *(float4*)&a8[0] = *(const float4*)&As[k][ty * 8];
      *(float4*)&a8[4] = *(const float4*)&As[k][ty * 8 + 4];
      *(float4*)&b8[0] = *(const float4*)&Bs[k][tx * 8];
      *(float4*)&b8[4] = *(const float4*)&Bs[k][tx * 8 + 4];
      #pragma unroll
      for (int i = 0; i < 8; ++i)
        #pragma unroll
        for (int j = 0; j < 8; ++j)
          acc[i][j] = fmaf(a8[i], b8[j], acc[i][j]);
    }
  }
  #pragma unroll
  for (int i = 0; i < 8; ++i) {
    float* cp = C + (size_t)(row0 + ty * 8 + i) * N + n0 + tx * 8;
    *(float4*)cp       = make_float4(acc[i][0], acc[i][1], acc[i][2], acc[i][3]);
    *(float4*)(cp + 4) = make_float4(acc[i][4], acc[i][5], acc[i][6], acc[i][7]);
  }
}

// ---------------------------------------------------------------------------
// In-place LayerNorm over each contiguous 64-wide head group. (unchanged)
// ---------------------------------------------------------------------------
__global__ __launch_bounds__(256) void ha_ln(
    float* __restrict__ Y, const float* __restrict__ gamma,
    const float* __restrict__ beta) {
  const int gtid = blockIdx.x * 256 + threadIdx.x;
  const int wv   = gtid >> 6;
  const int lane = gtid & 63;
  const size_t off = (size_t)(wv >> 4) * DMODEL + (size_t)(wv & 15) * HDIM + lane;
  const float v = Y[off];
  float s = v, s2 = v * v;
  #pragma unroll
  for (int m = 32; m >= 1; m >>= 1) {
    s  += __shfl_xor(s, m);
    s2 += __shfl_xor(s2, m);
  }
  const float mean = s * 0.015625f;
  const float var  = s2 * 0.015625f - mean * mean;
  const float rs   = rsqrtf(var + 1e-5f);
  Y[off] = (v - mean) * rs * gamma[lane] + beta[lane];
}

// ---------------------------------------------------------------------------
// Scan pass 1: per (bh, chunk) compute Asum, Bsum, Mlocal[e][d] = sum_s b_s (x) laexcl_s
// grid = BH*N_CHK = 1024 blocks, 256 threads.
// ---------------------------------------------------------------------------
__global__ __launch_bounds__(256) void ha_scan1(
    const float* __restrict__ An, const float* __restrict__ Bn,
    float* __restrict__ M, float* __restrict__ Asums, float* __restrict__ Bsums) {
  __shared__ float Al[64][68];
  __shared__ float Bl[64][68];
  __shared__ float sega[4][64];
  __shared__ float segb[4][64];
  const int bid = blockIdx.x;
  const int c   = bid & (N_CHK - 1);
  const int bh  = bid >> 5;
  const int b = bh >> 4, h = bh & 15;
  const int tid = threadIdx.x;
  const size_t rowbase = ((size_t)b * T_LEN + (size_t)c * L_CHK) * DMODEL + h * HDIM;

  #pragma unroll
  for (int i = 0; i < 4; ++i) {
    const int idx = tid + 256 * i;
    const int s = idx >> 4, c4 = idx & 15;
    float4 a4 = *(const float4*)(An + rowbase + (size_t)s * DMODEL + c4 * 4);
    float4 b4 = *(const float4*)(Bn + rowbase + (size_t)s * DMODEL + c4 * 4);
    *(float4*)&Al[s][c4 * 4] = a4;
    *(float4*)&Bl[s][c4 * 4] = b4;
  }
  __syncthreads();

  const int d = tid & 63, seg = tid >> 6;
  {
    float run = 0.f, runb = 0.f;
    for (int s = seg * 16; s < seg * 16 + 16; ++s) {
      const float va = Al[s][d];
      Al[s][d] = run;          // local-exclusive within segment
      run  += va;
      runb += Bl[s][d];
    }
    sega[seg][d] = run;
    segb[seg][d] = runb;
  }
  __syncthreads();
  {
    float off = 0.f;
    for (int q = 0; q < seg; ++q) off += sega[q][d];
    for (int s = seg * 16; s < seg * 16 + 16; ++s) Al[s][d] += off;
    if (seg == 0) {
      Asums[((size_t)bh * N_CHK + c) * 64 + d] =
          sega[0][d] + sega[1][d] + sega[2][d] + sega[3][d];
      Bsums[((size_t)bh * N_CHK + c) * 64 + d] =
          segb[0][d] + segb[1][d] + segb[2][d] + segb[3][d];
    }
  }
  __syncthreads();

  // Mlocal[e][d] = sum_s Bl[s][e] * Al[s][d]
  const int e0 = (tid >> 4) * 4, d0 = (tid & 15) * 4;
  float acc[4][4];
  #pragma unroll
  for (int i = 0; i < 4; ++i)
    #pragma unroll
    for (int j = 0; j < 4; ++j) acc[i][j] = 0.f;
  #pragma unroll 8
  for (int s = 0; s < 64; ++s) {
    const float4 bv = *(const float4*)&Bl[s][e0];
    const float4 av = *(const float4*)&Al[s][d0];
    const float bb_[4] = {bv.x, bv.y, bv.z, bv.w};
    const float aa_[4] = {av.x, av.y, av.z, av.w};
    #pragma unroll
    for (int i = 0; i < 4; ++i)
      #pragma unroll
      for (int j = 0; j < 4; ++j) acc[i][j] = fmaf(bb_[i], aa_[j], acc[i][j]);
  }
  float* Mp = M + ((size_t)bh * N_CHK + c) * 4096;
  #pragma unroll
  for (int i = 0; i < 4; ++i)
    *(float4*)(Mp + (e0 + i) * 64 + d0) =
        make_float4(acc[i][0], acc[i][1], acc[i][2], acc[i][3]);
}

// ---------------------------------------------------------------------------
// Scan pass 2: per bh, sequential over chunks:
//   write Soff_c (prefix) over Mlocal_c in place; Asums becomes Aoff in place.
// grid = BH = 32 blocks, 256 threads. Thread owns elems [tid*16, tid*16+16):
//   e = tid>>2 (const), d0 = (tid&3)*16.
// ---------------------------------------------------------------------------
__global__ __launch_bounds__(256) void ha_scan2(
    float* __restrict__ M, float* __restrict__ Asums,
    const float* __restrict__ Bsums) {
  __shared__ float aoff_sh[64];
  const int bh  = blockIdx.x;
  const int tid = threadIdx.x;
  const int e = tid >> 2, d0 = (tid & 3) * 16;
  float S[16];
  #pragma unroll
  for (int j = 0; j < 16; ++j) S[j] = 0.f;
  float aoff = 0.f;
  for (int c = 0; c < N_CHK; ++c) {
    if (tid < 64) {
      aoff_sh[tid] = aoff;
      const float as = Asums[((size_t)bh * N_CHK + c) * 64 + tid];
      Asums[((size_t)bh * N_CHK + c) * 64 + tid] = aoff;  // now Aoff_c
      aoff += as;
    }
    __syncthreads();
    float* Mp = M + ((size_t)bh * N_CHK + c) * 4096 + tid * 16;
    float m[16];
    #pragma unroll
    for (int j = 0; j < 16; j += 4) *(float4*)&m[j] = *(const float4*)(Mp + j);
    const float bs = Bsums[((size_t)bh * N_CHK + c) * 64 + e];
    #pragma unroll
    for (int j = 0; j < 16; j += 4)
      *(float4*)(Mp + j) = make_float4(S[j], S[j + 1], S[j + 2], S[j + 3]);
    #pragma unroll
    for (int j = 0; j < 16; ++j) S[j] += fmaf(bs, aoff_sh[d0 + j], m[j]);
    __syncthreads();
  }
}

// ---------------------------------------------------------------------------
// Scan pass 3: per (bh, chunk):
//   G = Aoff_c + local-exclusive-cumsum(A);  Pt[s][t] = (s<=t) ? q_t . g_s : 0
//   O[t][e] = sum_s Pt[s][t]*B[s][e] + sum_d Qt[d][t]*Soff[e][d]
// Writes O in-place over Qn (block touches only its own tile).
// grid = 1024 blocks, 256 threads.
// ---------------------------------------------------------------------------
__global__ __launch_bounds__(256) void ha_scan3(
    float* __restrict__ Qn, const float* __restrict__ An,
    const float* __restrict__ Bn, const float* __restrict__ Soff,
    const float* __restrict__ Aoff) {
  __shared__ float Qt[64][68];   // [k][t]
  __shared__ float Gt[64][68];   // [d][s]; reloaded as St[d][e] after stage A
  __shared__ float Bl[64][68];   // [s][e]
  __shared__ float Pt[64][68];   // [s][t]
  const int bid = blockIdx.x;
  const int c   = bid & (N_CHK - 1);
  const int bh  = bid >> 5;
  const int b = bh >> 4, h = bh & 15;
  const int tid = threadIdx.x;
  const size_t rowbase = ((size_t)b * T_LEN + (size_t)c * L_CHK) * DMODEL + h * HDIM;

  #pragma unroll
  for (int i = 0; i < 4; ++i) {
    const int idx = tid + 256 * i;
    const int t = idx >> 4, c4 = idx & 15;
    float4 q4 = *(const float4*)(Qn + rowbase + (size_t)t * DMODEL + c4 * 4);
    float4 a4 = *(const float4*)(An + rowbase + (size_t)t * DMODEL + c4 * 4);
    float4 b4 = *(const float4*)(Bn + rowbase + (size_t)t * DMODEL + c4 * 4);
    Qt[c4 * 4 + 0][t] = q4.x; Qt[c4 * 4 + 1][t] = q4.y;
    Qt[c4 * 4 + 2][t] = q4.z; Qt[c4 * 4 + 3][t] = q4.w;
    Gt[c4 * 4 + 0][t] = a4.x; Gt[c4 * 4 + 1][t] = a4.y;
    Gt[c4 * 4 + 2][t] = a4.z; Gt[c4 * 4 + 3][t] = a4.w;
    *(float4*)&Bl[t][c4 * 4] = b4;
  }
  __syncthreads();

  if (tid < 64) {   // exclusive cumsum along s (row of Gt), seeded with Aoff
    float run = Aoff[((size_t)bh * N_CHK + c) * 64 + tid];
    for (int s = 0; s < 64; ++s) {
      const float v = Gt[tid][s];
      Gt[tid][s] = run;
      run += v;
    }
  }
  __syncthreads();

  const int tt = tid >> 4, ss = tid & 15;
  const int t0 = tt * 4, s0 = ss * 4;
  {
    float p[4][4];
    #pragma unroll
    for (int i = 0; i < 4; ++i)
      #pragma unroll
      for (int j = 0; j < 4; ++j) p[i][j] = 0.f;
    #pragma unroll 8
    for (int k = 0; k < 64; ++k) {
      const float4 qv = *(const float4*)&Qt[k][t0];
      const float4 gv = *(const float4*)&Gt[k][s0];
      const float qq[4] = {qv.x, qv.y, qv.z, qv.w};
      const float gg[4] = {gv.x, gv.y, gv.z, gv.w};
      #pragma unroll
      for (int i = 0; i < 4; ++i)
        #pragma unroll
        for (int j = 0; j < 4; ++j) p[i][j] = fmaf(qq[i], gg[j], p[i][j]);
    }
    #pragma unroll
    for (int i = 0; i < 4; ++i)
      #pragma unroll
      for (int j = 0; j < 4; ++j)
        Pt[s0 + j][t0 + i] = (s0 + j <= t0 + i) ? p[i][j] : 0.f;
  }
  __syncthreads();

  // reload Gt slot with Soff transposed: St[d][e]
  const float* Sg = Soff + ((size_t)bh * N_CHK + c) * 4096;
  #pragma unroll
  for (int i = 0; i < 4; ++i) {
    const int idx = tid + 256 * i;
    const int e = idx >> 4, d4 = idx & 15;
    float4 s4 = *(const float4*)(Sg + (size_t)e * 64 + d4 * 4);
    Gt[d4 * 4 + 0][e] = s4.x; Gt[d4 * 4 + 1][e] = s4.y;
    Gt[d4 * 4 + 2][e] = s4.z; Gt[d4 * 4 + 3][e] = s4.w;
  }
  __syncthreads();

  const int e0 = s0;   // same 4-wide split, now over e
  float o[4][4];
  #pragma unroll
  for (int i = 0; i < 4; ++i)
    #pragma unroll
    for (int j = 0; j < 4; ++j) o[i][j] = 0.f;
  #pragma unroll 8
  for (int s = 0; s < 64; ++s) {
    const float4 pv = *(const float4*)&Pt[s][t0];
    const float4 bv = *(const float4*)&Bl[s][e0];
    const float pp[4] = {pv.x, pv.y, pv.z, pv.w};
    const float bb_[4] = {bv.x, bv.y, bv.z, bv.w};
    #pragma unroll
    for (int i = 0; i < 4; ++i)
      #pragma unroll
      for (int j = 0; j < 4; ++j) o[i][j] = fmaf(pp[i], bb_[j], o[i][j]);
  }
  #pragma unroll 8
  for (int dd = 0; dd < 64; ++dd) {
    const float4 qv = *(const float4*)&Qt[dd][t0];
    const float4 sv = *(const float4*)&Gt[dd][e0];
    const float qq[4] = {qv.x, qv.y, qv.z, qv.w};
    const float sS[4] = {sv.x, sv.y, sv.z, sv.w};
    #pragma unroll
    for (int i = 0; i < 4; ++i)
      #pragma unroll
      for (int j = 0; j < 4; ++j) o[i][j] = fmaf(qq[i], sS[j], o[i][j]);
  }
  #pragma unroll
  for (int i = 0; i < 4; ++i)
    *(float4*)(Qn + rowbase + (size_t)(t0 + i) * DMODEL + e0) =
        make_float4(o[i][0], o[i][1], o[i][2], o[i][3]);
}

// ---------------------------------------------------------------------------
extern "C" void kernel_launch(void* const* d_in, const int* in_sizes, int n_in,
                              void* d_out, int out_size, void* d_ws,
                              size_t ws_size, hipStream_t stream) {
  const float* x  = (const float*)d_in[0];
  const float* Wq = (const float*)d_in[1];
  const float* Wa = (const float*)d_in[2];
  const float* Wb = (const float*)d_in[3];
  const float* Wo = (const float*)d_in[4];
  const float* qg = (const float*)d_in[5];
  const float* qb = (const float*)d_in[6];
  const float* ag = (const float*)d_in[7];
  const float* ab = (const float*)d_in[8];
  const float* bg = (const float*)d_in[9];
  const float* bb = (const float*)d_in[10];
  float* out = (float*)d_out;

  float* ws = (float*)d_ws;
  float* qn = ws;                                    // 16 MB
  float* an = qn + (size_t)MROWS * DMODEL;           // 16 MB
  float* bn = an + (size_t)MROWS * DMODEL;           // 16 MB
  float* asums = bn + (size_t)MROWS * DMODEL;        // 256 KB
  float* bsums = asums + (size_t)BH * N_CHK * 64;    // 256 KB
  float* Mbuf  = out;  // d_out doubles as Mlocal/Soff scratch (16 MB exactly);
                       // consumed by ha_scan3 before the final GEMM overwrites it.

  const dim3 ggrid(DMODEL / 128, MROWS / 128);       // (8, 32)
  const int ln_blocks = (MROWS * NHEAD * 64) / 256;  // 16384

  ha_gemm_f32<<<ggrid, 256, 0, stream>>>(x, Wq, qn);
  ha_ln<<<ln_blocks, 256, 0, stream>>>(qn, qg, qb);
  ha_gemm_f32<<<ggrid, 256, 0, stream>>>(x, Wa, an);
  ha_ln<<<ln_blocks, 256, 0, stream>>>(an, ag, ab);
  ha_gemm_f32<<<ggrid, 256, 0, stream>>>(x, Wb, bn);
  ha_ln<<<ln_blocks, 256, 0, stream>>>(bn, bg, bb);

  ha_scan1<<<BH * N_CHK, 256, 0, stream>>>(an, bn, Mbuf, asums, bsums);
  ha_scan2<<<BH, 256, 0, stream>>>(Mbuf, asums, bsums);
  ha_scan3<<<BH * N_CHK, 256, 0, stream>>>(qn, an, bn, Mbuf, asums);

  ha_gemm_f32<<<ggrid, 256, 0, stream>>>(qn, Wo, out);
}

// Round 3
// 299.098 us; speedup vs baseline: 4.5529x; 2.7470x over previous
//
#include <hip/hip_runtime.h>
#include <hip/hip_bf16.h>

#define T_LEN  2048
#define NHEAD  16
#define HDIM   64
#define DMODEL 1024
#define BATCH  2
#define MROWS  4096   // B*T
#define L_CHK  64
#define N_CHK  (T_LEN / L_CHK)   // 32
#define BH     (BATCH * NHEAD)   // 32

typedef __attribute__((ext_vector_type(8))) short short8;
typedef __attribute__((ext_vector_type(4))) float f32x4;
typedef __attribute__((ext_vector_type(4))) unsigned short ushort4v;

// async global->LDS, 16B per lane; LDS dest = wave-uniform base + lane*16
#define GLDS(GP, LP) __builtin_amdgcn_global_load_lds( \
    (__attribute__((address_space(1))) void*)(void*)(GP), \
    (__attribute__((address_space(3))) void*)(LP), 16, 0, 0)

__device__ __forceinline__ unsigned short f2bf(float f) {
  union { float f; unsigned int u; } v; v.f = f;
  unsigned int r = v.u + 0x7FFFu + ((v.u >> 16) & 1u);   // RNE
  return (unsigned short)(r >> 16);
}

// ---------------------------------------------------------------------------
// x fp32 -> bf16 (4096x1024)
// ---------------------------------------------------------------------------
__global__ __launch_bounds__(256) void ha_convx(
    const float* __restrict__ X, short* __restrict__ Xb) {
  const size_t idx = (size_t)(blockIdx.x * 256 + threadIdx.x) * 8;
  float4 v0 = *(const float4*)(X + idx);
  float4 v1 = *(const float4*)(X + idx + 4);
  short8 o;
  o[0] = (short)f2bf(v0.x); o[1] = (short)f2bf(v0.y);
  o[2] = (short)f2bf(v0.z); o[3] = (short)f2bf(v0.w);
  o[4] = (short)f2bf(v1.x); o[5] = (short)f2bf(v1.y);
  o[6] = (short)f2bf(v1.z); o[7] = (short)f2bf(v1.w);
  *(short8*)(Xb + idx) = o;
}

// ---------------------------------------------------------------------------
// W[K=1024][N=1024] fp32 -> WT[n_base+n][k] bf16 (transpose + convert)
// ---------------------------------------------------------------------------
__global__ __launch_bounds__(256) void ha_convT(
    const float* __restrict__ W, short* __restrict__ WT, int n_base) {
  __shared__ float tile[64][65];
  const int k0 = blockIdx.y * 64, n0 = blockIdx.x * 64;
  const int tid = threadIdx.x;
  #pragma unroll
  for (int p = 0; p < 4; ++p) {
    const int r  = p * 16 + (tid >> 4);
    const int c4 = (tid & 15) * 4;
    float4 v = *(const float4*)(W + (size_t)(k0 + r) * DMODEL + n0 + c4);
    tile[r][c4 + 0] = v.x; tile[r][c4 + 1] = v.y;
    tile[r][c4 + 2] = v.z; tile[r][c4 + 3] = v.w;
  }
  __syncthreads();
  #pragma unroll
  for (int p = 0; p < 4; ++p) {
    const int n = p * 16 + (tid >> 4);
    const int c = (tid & 15) * 4;
    ushort4v o = { f2bf(tile[c + 0][n]), f2bf(tile[c + 1][n]),
                   f2bf(tile[c + 2][n]), f2bf(tile[c + 3][n]) };
    *(ushort4v*)(WT + (size_t)(n_base + n0 + n) * DMODEL + k0 + c) = o;
  }
}

// ---------------------------------------------------------------------------
// Fused QAB projection GEMM: C[M,3072] = Xb[M,1024] @ WqabT[3072,1024]^T
// bf16 MFMA 16x16x32, 128x128 tile, BK=32, global_load_lds width 16.
// Output demuxed to q/a/b fp32 buffers (block entirely within one of them).
// grid (24, 32) = 768 blocks -> 3 blocks/CU.
// ---------------------------------------------------------------------------
__global__ __launch_bounds__(256) void ha_gemm_qab(
    const short* __restrict__ Ab, const short* __restrict__ Bt,
    float* __restrict__ q, float* __restrict__ a, float* __restrict__ bOut) {
  __shared__ short As[128 * 32] __attribute__((aligned(16)));
  __shared__ short Bs[128 * 32] __attribute__((aligned(16)));
  const int tid = threadIdx.x;
  const int wave = tid >> 6, lane = tid & 63;
  const int m0  = blockIdx.y * 128;
  const int n0g = blockIdx.x * 128;           // [0, 3072)
  float* Cbuf = (n0g < 1024) ? q : (n0g < 2048) ? a : bOut;
  const int n0 = n0g & 1023;

  const int srow = wave * 32 + (lane >> 2);
  const int scol = (lane & 3) * 8;
  const short* agp = Ab + (size_t)(m0 + srow) * DMODEL + scol;
  const short* bgp = Bt + (size_t)(n0g + srow) * DMODEL + scol;
  short* alp = As + wave * 32 * 32;
  short* blp = Bs + wave * 32 * 32;

  f32x4 acc[4][4] = {};
  const int lm = lane & 15, kh = lane >> 4;
  const int wm = (wave >> 1) * 64, wn = (wave & 1) * 64;

  for (int k0 = 0; k0 < DMODEL; k0 += 32) {
    GLDS(agp,               alp);
    GLDS(agp + 16 * DMODEL, alp + 16 * 32);
    GLDS(bgp,               blp);
    GLDS(bgp + 16 * DMODEL, blp + 16 * 32);
    agp += 32; bgp += 32;
    __syncthreads();
    short8 af[4], bf[4];
    #pragma unroll
    for (int i = 0; i < 4; ++i) {
      af[i] = *(const short8*)&As[(wm + i * 16 + lm) * 32 + kh * 8];
      bf[i] = *(const short8*)&Bs[(wn + i * 16 + lm) * 32 + kh * 8];
    }
    #pragma unroll
    for (int i = 0; i < 4; ++i)
      #pragma unroll
      for (int j = 0; j < 4; ++j)
        acc[i][j] = __builtin_amdgcn_mfma_f32_16x16x32_bf16(
            af[i], bf[j], acc[i][j], 0, 0, 0);
    __syncthreads();
  }
  #pragma unroll
  for (int i = 0; i < 4; ++i)
    #pragma unroll
    for (int j = 0; j < 4; ++j) {
      float* cp = Cbuf + (size_t)(m0 + wm + i * 16 + kh * 4) * DMODEL +
                  n0 + wn + j * 16 + lm;
      #pragma unroll
      for (int r = 0; r < 4; ++r) cp[(size_t)r * DMODEL] = acc[i][j][r];
    }
}

// ---------------------------------------------------------------------------
// Output GEMM: C[M,1024] = Ob[M,1024](bf16) @ WoT[1024,1024]^T
// 128x64 tile -> grid (16,32) = 512 blocks (2/CU).
// ---------------------------------------------------------------------------
__global__ __launch_bounds__(256) void ha_gemm_out(
    const short* __restrict__ Ab, const short* __restrict__ Bt,
    float* __restrict__ C) {
  __shared__ short As[128 * 32] __attribute__((aligned(16)));
  __shared__ short Bs[64 * 32] __attribute__((aligned(16)));
  const int tid = threadIdx.x;
  const int wave = tid >> 6, lane = tid & 63;
  const int m0 = blockIdx.y * 128;
  const int n0 = blockIdx.x * 64;

  const int arow = wave * 32 + (lane >> 2);
  const int brow = wave * 16 + (lane >> 2);
  const int scol = (lane & 3) * 8;
  const short* agp = Ab + (size_t)(m0 + arow) * DMODEL + scol;
  const short* bgp = Bt + (size_t)(n0 + brow) * DMODEL + scol;
  short* alp = As + wave * 32 * 32;
  short* blp = Bs + wave * 16 * 32;

  f32x4 acc[4][2] = {};
  const int lm = lane & 15, kh = lane >> 4;
  const int wm = (wave >> 1) * 64, wn = (wave & 1) * 32;

  for (int k0 = 0; k0 < DMODEL; k0 += 32) {
    GLDS(agp,               alp);
    GLDS(agp + 16 * DMODEL, alp + 16 * 32);
    GLDS(bgp,               blp);
    agp += 32; bgp += 32;
    __syncthreads();
    short8 af[4], bf2[2];
    #pragma unroll
    for (int i = 0; i < 4; ++i)
      af[i] = *(const short8*)&As[(wm + i * 16 + lm) * 32 + kh * 8];
    #pragma unroll
    for (int j = 0; j < 2; ++j)
      bf2[j] = *(const short8*)&Bs[(wn + j * 16 + lm) * 32 + kh * 8];
    #pragma unroll
    for (int i = 0; i < 4; ++i)
      #pragma unroll
      for (int j = 0; j < 2; ++j)
        acc[i][j] = __builtin_amdgcn_mfma_f32_16x16x32_bf16(
            af[i], bf2[j], acc[i][j], 0, 0, 0);
    __syncthreads();
  }
  #pragma unroll
  for (int i = 0; i < 4; ++i)
    #pragma unroll
    for (int j = 0; j < 2; ++j) {
      float* cp = C + (size_t)(m0 + wm + i * 16 + kh * 4) * DMODEL +
                  n0 + wn + j * 16 + lm;
      #pragma unroll
      for (int r = 0; r < 4; ++r) cp[(size_t)r * DMODEL] = acc[i][j][r];
    }
}

// ---------------------------------------------------------------------------
// In-place LayerNorm over each contiguous 64-wide head group. (unchanged)
// ---------------------------------------------------------------------------
__global__ __launch_bounds__(256) void ha_ln(
    float* __restrict__ Y, const float* __restrict__ gamma,
    const float* __restrict__ beta) {
  const int gtid = blockIdx.x * 256 + threadIdx.x;
  const int wv   = gtid >> 6;
  const int lane = gtid & 63;
  const size_t off = (size_t)(wv >> 4) * DMODEL + (size_t)(wv & 15) * HDIM + lane;
  const float v = Y[off];
  float s = v, s2 = v * v;
  #pragma unroll
  for (int m = 32; m >= 1; m >>= 1) {
    s  += __shfl_xor(s, m);
    s2 += __shfl_xor(s2, m);
  }
  const float mean = s * 0.015625f;
  const float var  = s2 * 0.015625f - mean * mean;
  const float rs   = rsqrtf(var + 1e-5f);
  Y[off] = (v - mean) * rs * gamma[lane] + beta[lane];
}

// ---------------------------------------------------------------------------
// Scan pass 1 (unchanged)
// ---------------------------------------------------------------------------
__global__ __launch_bounds__(256) void ha_scan1(
    const float* __restrict__ An, const float* __restrict__ Bn,
    float* __restrict__ M, float* __restrict__ Asums, float* __restrict__ Bsums) {
  __shared__ float Al[64][68];
  __shared__ float Bl[64][68];
  __shared__ float sega[4][64];
  __shared__ float segb[4][64];
  const int bid = blockIdx.x;
  const int c   = bid & (N_CHK - 1);
  const int bh  = bid >> 5;
  const int b = bh >> 4, h = bh & 15;
  const int tid = threadIdx.x;
  const size_t rowbase = ((size_t)b * T_LEN + (size_t)c * L_CHK) * DMODEL + h * HDIM;

  #pragma unroll
  for (int i = 0; i < 4; ++i) {
    const int idx = tid + 256 * i;
    const int s = idx >> 4, c4 = idx & 15;
    float4 a4 = *(const float4*)(An + rowbase + (size_t)s * DMODEL + c4 * 4);
    float4 b4 = *(const float4*)(Bn + rowbase + (size_t)s * DMODEL + c4 * 4);
    *(float4*)&Al[s][c4 * 4] = a4;
    *(float4*)&Bl[s][c4 * 4] = b4;
  }
  __syncthreads();

  const int d = tid & 63, seg = tid >> 6;
  {
    float run = 0.f, runb = 0.f;
    for (int s = seg * 16; s < seg * 16 + 16; ++s) {
      const float va = Al[s][d];
      Al[s][d] = run;
      run  += va;
      runb += Bl[s][d];
    }
    sega[seg][d] = run;
    segb[seg][d] = runb;
  }
  __syncthreads();
  {
    float off = 0.f;
    for (int qq = 0; qq < seg; ++qq) off += sega[qq][d];
    for (int s = seg * 16; s < seg * 16 + 16; ++s) Al[s][d] += off;
    if (seg == 0) {
      Asums[((size_t)bh * N_CHK + c) * 64 + d] =
          sega[0][d] + sega[1][d] + sega[2][d] + sega[3][d];
      Bsums[((size_t)bh * N_CHK + c) * 64 + d] =
          segb[0][d] + segb[1][d] + segb[2][d] + segb[3][d];
    }
  }
  __syncthreads();

  const int e0 = (tid >> 4) * 4, d0 = (tid & 15) * 4;
  float acc[4][4];
  #pragma unroll
  for (int i = 0; i < 4; ++i)
    #pragma unroll
    for (int j = 0; j < 4; ++j) acc[i][j] = 0.f;
  #pragma unroll 8
  for (int s = 0; s < 64; ++s) {
    const float4 bv = *(const float4*)&Bl[s][e0];
    const float4 av = *(const float4*)&Al[s][d0];
    const float bb_[4] = {bv.x, bv.y, bv.z, bv.w};
    const float aa_[4] = {av.x, av.y, av.z, av.w};
    #pragma unroll
    for (int i = 0; i < 4; ++i)
      #pragma unroll
      for (int j = 0; j < 4; ++j) acc[i][j] = fmaf(bb_[i], aa_[j], acc[i][j]);
  }
  float* Mp = M + ((size_t)bh * N_CHK + c) * 4096;
  #pragma unroll
  for (int i = 0; i < 4; ++i)
    *(float4*)(Mp + (e0 + i) * 64 + d0) =
        make_float4(acc[i][0], acc[i][1], acc[i][2], acc[i][3]);
}

// ---------------------------------------------------------------------------
// Scan pass 2 (unchanged)
// ---------------------------------------------------------------------------
__global__ __launch_bounds__(256) void ha_scan2(
    float* __restrict__ M, float* __restrict__ Asums,
    const float* __restrict__ Bsums) {
  __shared__ float aoff_sh[64];
  const int bh  = blockIdx.x;
  const int tid = threadIdx.x;
  const int e = tid >> 2, d0 = (tid & 3) * 16;
  float S[16];
  #pragma unroll
  for (int j = 0; j < 16; ++j) S[j] = 0.f;
  float aoff = 0.f;
  for (int c = 0; c < N_CHK; ++c) {
    if (tid < 64) {
      aoff_sh[tid] = aoff;
      const float as = Asums[((size_t)bh * N_CHK + c) * 64 + tid];
      Asums[((size_t)bh * N_CHK + c) * 64 + tid] = aoff;
      aoff += as;
    }
    __syncthreads();
    float* Mp = M + ((size_t)bh * N_CHK + c) * 4096 + tid * 16;
    float m[16];
    #pragma unroll
    for (int j = 0; j < 16; j += 4) *(float4*)&m[j] = *(const float4*)(Mp + j);
    const float bs = Bsums[((size_t)bh * N_CHK + c) * 64 + e];
    #pragma unroll
    for (int j = 0; j < 16; j += 4)
      *(float4*)(Mp + j) = make_float4(S[j], S[j + 1], S[j + 2], S[j + 3]);
    #pragma unroll
    for (int j = 0; j < 16; ++j) S[j] += fmaf(bs, aoff_sh[d0 + j], m[j]);
    __syncthreads();
  }
}

// ---------------------------------------------------------------------------
// Scan pass 3: as before, but output O is written as bf16 to Ob.
// ---------------------------------------------------------------------------
__global__ __launch_bounds__(256) void ha_scan3(
    const float* __restrict__ Qn, const float* __restrict__ An,
    const float* __restrict__ Bn, const float* __restrict__ Soff,
    const float* __restrict__ Aoff, short* __restrict__ Ob) {
  __shared__ float Qt[64][68];
  __shared__ float Gt[64][68];
  __shared__ float Bl[64][68];
  __shared__ float Pt[64][68];
  const int bid = blockIdx.x;
  const int c   = bid & (N_CHK - 1);
  const int bh  = bid >> 5;
  const int b = bh >> 4, h = bh & 15;
  const int tid = threadIdx.x;
  const size_t rowbase = ((size_t)b * T_LEN + (size_t)c * L_CHK) * DMODEL + h * HDIM;

  #pragma unroll
  for (int i = 0; i < 4; ++i) {
    const int idx = tid + 256 * i;
    const int t = idx >> 4, c4 = idx & 15;
    float4 q4 = *(const float4*)(Qn + rowbase + (size_t)t * DMODEL + c4 * 4);
    float4 a4 = *(const float4*)(An + rowbase + (size_t)t * DMODEL + c4 * 4);
    float4 b4 = *(const float4*)(Bn + rowbase + (size_t)t * DMODEL + c4 * 4);
    Qt[c4 * 4 + 0][t] = q4.x; Qt[c4 * 4 + 1][t] = q4.y;
    Qt[c4 * 4 + 2][t] = q4.z; Qt[c4 * 4 + 3][t] = q4.w;
    Gt[c4 * 4 + 0][t] = a4.x; Gt[c4 * 4 + 1][t] = a4.y;
    Gt[c4 * 4 + 2][t] = a4.z; Gt[c4 * 4 + 3][t] = a4.w;
    *(float4*)&Bl[t][c4 * 4] = b4;
  }
  __syncthreads();

  if (tid < 64) {
    float run = Aoff[((size_t)bh * N_CHK + c) * 64 + tid];
    for (int s = 0; s < 64; ++s) {
      const float v = Gt[tid][s];
      Gt[tid][s] = run;
      run += v;
    }
  }
  __syncthreads();

  const int tt = tid >> 4, ss = tid & 15;
  const int t0 = tt * 4, s0 = ss * 4;
  {
    float p[4][4];
    #pragma unroll
    for (int i = 0; i < 4; ++i)
      #pragma unroll
      for (int j = 0; j < 4; ++j) p[i][j] = 0.f;
    #pragma unroll 8
    for (int k = 0; k < 64; ++k) {
      const float4 qv = *(const float4*)&Qt[k][t0];
      const float4 gv = *(const float4*)&Gt[k][s0];
      const float qq[4] = {qv.x, qv.y, qv.z, qv.w};
      const float gg[4] = {gv.x, gv.y, gv.z, gv.w};
      #pragma unroll
      for (int i = 0; i < 4; ++i)
        #pragma unroll
        for (int j = 0; j < 4; ++j) p[i][j] = fmaf(qq[i], gg[j], p[i][j]);
    }
    #pragma unroll
    for (int i = 0; i < 4; ++i)
      #pragma unroll
      for (int j = 0; j < 4; ++j)
        Pt[s0 + j][t0 + i] = (s0 + j <= t0 + i) ? p[i][j] : 0.f;
  }
  __syncthreads();

  const float* Sg = Soff + ((size_t)bh * N_CHK + c) * 4096;
  #pragma unroll
  for (int i = 0; i < 4; ++i) {
    const int idx = tid + 256 * i;
    const int e = idx >> 4, d4 = idx & 15;
    float4 s4 = *(const float4*)(Sg + (size_t)e * 64 + d4 * 4);
    Gt[d4 * 4 + 0][e] = s4.x; Gt[d4 * 4 + 1][e] = s4.y;
    Gt[d4 * 4 + 2][e] = s4.z; Gt[d4 * 4 + 3][e] = s4.w;
  }
  __syncthreads();

  const int e0 = s0;
  float o[4][4];
  #pragma unroll
  for (int i = 0; i < 4; ++i)
    #pragma unroll
    for (int j = 0; j < 4; ++j) o[i][j] = 0.f;
  #pragma unroll 8
  for (int s = 0; s < 64; ++s) {
    const float4 pv = *(const float4*)&Pt[s][t0];
    const float4 bv = *(const float4*)&Bl[s][e0];
    const float pp[4] = {pv.x, pv.y, pv.z, pv.w};
    const float bb_[4] = {bv.x, bv.y, bv.z, bv.w};
    #pragma unroll
    for (int i = 0; i < 4; ++i)
      #pragma unroll
      for (int j = 0; j < 4; ++j) o[i][j] = fmaf(pp[i], bb_[j], o[i][j]);
  }
  #pragma unroll 8
  for (int dd = 0; dd < 64; ++dd) {
    const float4 qv = *(const float4*)&Qt[dd][t0];
    const float4 sv = *(const float4*)&Gt[dd][e0];
    const float qq[4] = {qv.x, qv.y, qv.z, qv.w};
    const float sS[4] = {sv.x, sv.y, sv.z, sv.w};
    #pragma unroll
    for (int i = 0; i < 4; ++i)
      #pragma unroll
      for (int j = 0; j < 4; ++j) o[i][j] = fmaf(qq[i], sS[j], o[i][j]);
  }
  #pragma unroll
  for (int i = 0; i < 4; ++i) {
    ushort4v o4 = { f2bf(o[i][0]), f2bf(o[i][1]), f2bf(o[i][2]), f2bf(o[i][3]) };
    *(ushort4v*)(Ob + rowbase + (size_t)(t0 + i) * DMODEL + e0) = o4;
  }
}

// ---------------------------------------------------------------------------
extern "C" void kernel_launch(void* const* d_in, const int* in_sizes, int n_in,
                              void* d_out, int out_size, void* d_ws,
                              size_t ws_size, hipStream_t stream) {
  const float* x  = (const float*)d_in[0];
  const float* Wq = (const float*)d_in[1];
  const float* Wa = (const float*)d_in[2];
  const float* Wb = (const float*)d_in[3];
  const float* Wo = (const float*)d_in[4];
  const float* qg = (const float*)d_in[5];
  const float* qb = (const float*)d_in[6];
  const float* ag = (const float*)d_in[7];
  const float* ab = (const float*)d_in[8];
  const float* bg = (const float*)d_in[9];
  const float* bb = (const float*)d_in[10];
  float* out = (float*)d_out;

  // workspace layout (64 MB total, overlays noted):
  float* ws = (float*)d_ws;
  float* qn = ws;                                     // [0,16) MB fp32
  float* an = qn + (size_t)MROWS * DMODEL;            // [16,32) MB
  float* bn = an + (size_t)MROWS * DMODEL;            // [32,48) MB
  short* xb  = (short*)(bn + (size_t)MROWS * DMODEL); // [48,56) MB bf16
  short* obb = xb;                                    // overlay: xb dead after QAB GEMM
  short* wqabT = (short*)((char*)d_ws + 56u * 1024 * 1024);  // [56,62) MB bf16
  float* asums = (float*)wqabT;                       // overlay: wqabT dead after QAB GEMM
  float* bsums = asums + (size_t)BH * N_CHK * 64;     // +256 KB
  short* woT   = (short*)((char*)d_ws + 62u * 1024 * 1024);  // [62,64) MB bf16
  float* Mbuf  = out;   // d_out doubles as Mlocal/Soff scratch (16 MB exactly)

  const int ln_blocks = (MROWS * NHEAD * 64) / 256;   // 16384

  ha_convx<<<(MROWS * DMODEL) / (256 * 8), 256, 0, stream>>>(x, xb);
  ha_convT<<<dim3(16, 16), 256, 0, stream>>>(Wq, wqabT, 0);
  ha_convT<<<dim3(16, 16), 256, 0, stream>>>(Wa, wqabT, 1024);
  ha_convT<<<dim3(16, 16), 256, 0, stream>>>(Wb, wqabT, 2048);
  ha_convT<<<dim3(16, 16), 256, 0, stream>>>(Wo, woT, 0);

  ha_gemm_qab<<<dim3(24, 32), 256, 0, stream>>>(xb, wqabT, qn, an, bn);
  ha_ln<<<ln_blocks, 256, 0, stream>>>(qn, qg, qb);
  ha_ln<<<ln_blocks, 256, 0, stream>>>(an, ag, ab);
  ha_ln<<<ln_blocks, 256, 0, stream>>>(bn, bg, bb);

  ha_scan1<<<BH * N_CHK, 256, 0, stream>>>(an, bn, Mbuf, asums, bsums);
  ha_scan2<<<BH, 256, 0, stream>>>(Mbuf, asums, bsums);
  ha_scan3<<<BH * N_CHK, 256, 0, stream>>>(qn, an, bn, Mbuf, asums, obb);

  ha_gemm_out<<<dim3(16, 32), 256, 0, stream>>>(obb, woT, out);
}

// Round 5
// 205.160 us; speedup vs baseline: 6.6375x; 1.4579x over previous
//
#include <hip/hip_runtime.h>
#include <hip/hip_bf16.h>

#define T_LEN  2048
#define NHEAD  16
#define HDIM   64
#define DMODEL 1024
#define BATCH  2
#define MROWS  4096   // B*T
#define L_CHK  64
#define N_CHK  (T_LEN / L_CHK)   // 32
#define BH     (BATCH * NHEAD)   // 32

typedef __attribute__((ext_vector_type(8))) short short8;
typedef __attribute__((ext_vector_type(4))) float f32x4;
typedef __attribute__((ext_vector_type(4))) unsigned short ushort4v;

// async global->LDS, 16B per lane; LDS dest = wave-uniform base + lane*16
#define GLDS(GP, LP) __builtin_amdgcn_global_load_lds( \
    (__attribute__((address_space(1))) void*)(void*)(GP), \
    (__attribute__((address_space(3))) void*)(LP), 16, 0, 0)

__device__ __forceinline__ unsigned short f2bf(float f) {
  union { float f; unsigned int u; } v; v.f = f;
  unsigned int r = v.u + 0x7FFFu + ((v.u >> 16) & 1u);   // RNE
  return (unsigned short)(r >> 16);
}
__device__ __forceinline__ float bf2f(short s) {
  union { unsigned int u; float f; } v;
  v.u = ((unsigned int)(unsigned short)s) << 16;
  return v.f;
}

// ---------------------------------------------------------------------------
// x fp32 -> bf16 (4096x1024)
// ---------------------------------------------------------------------------
__global__ __launch_bounds__(256) void ha_convx(
    const float* __restrict__ X, short* __restrict__ Xb) {
  const size_t idx = (size_t)(blockIdx.x * 256 + threadIdx.x) * 8;
  float4 v0 = *(const float4*)(X + idx);
  float4 v1 = *(const float4*)(X + idx + 4);
  short8 o;
  o[0] = (short)f2bf(v0.x); o[1] = (short)f2bf(v0.y);
  o[2] = (short)f2bf(v0.z); o[3] = (short)f2bf(v0.w);
  o[4] = (short)f2bf(v1.x); o[5] = (short)f2bf(v1.y);
  o[6] = (short)f2bf(v1.z); o[7] = (short)f2bf(v1.w);
  *(short8*)(Xb + idx) = o;
}

// ---------------------------------------------------------------------------
// All four weight transposes in one launch: grid (16,16,4).
// z<3 -> wqabT at z*1024 rows; z==3 -> woT.
// ---------------------------------------------------------------------------
__global__ __launch_bounds__(256) void ha_convT4(
    const float* __restrict__ Wq, const float* __restrict__ Wa,
    const float* __restrict__ Wb, const float* __restrict__ Wo,
    short* __restrict__ wqabT, short* __restrict__ woT) {
  __shared__ float tile[64][65];
  const int z = blockIdx.z;
  const float* W = (z == 0) ? Wq : (z == 1) ? Wa : (z == 2) ? Wb : Wo;
  short* WT = (z < 3) ? wqabT + (size_t)z * 1024 * DMODEL : woT;
  const int k0 = blockIdx.y * 64, n0 = blockIdx.x * 64;
  const int tid = threadIdx.x;
  #pragma unroll
  for (int p = 0; p < 4; ++p) {
    const int r  = p * 16 + (tid >> 4);
    const int c4 = (tid & 15) * 4;
    float4 v = *(const float4*)(W + (size_t)(k0 + r) * DMODEL + n0 + c4);
    tile[r][c4 + 0] = v.x; tile[r][c4 + 1] = v.y;
    tile[r][c4 + 2] = v.z; tile[r][c4 + 3] = v.w;
  }
  __syncthreads();
  #pragma unroll
  for (int p = 0; p < 4; ++p) {
    const int n = p * 16 + (tid >> 4);
    const int c = (tid & 15) * 4;
    ushort4v o = { f2bf(tile[c + 0][n]), f2bf(tile[c + 1][n]),
                   f2bf(tile[c + 2][n]), f2bf(tile[c + 3][n]) };
    *(ushort4v*)(WT + (size_t)(n0 + n) * DMODEL + k0 + c) = o;
  }
}

// ---------------------------------------------------------------------------
// Fused QAB projection GEMM + per-head LayerNorm epilogue, bf16 out.
// C[M,3072] = Xb[M,1024] @ WqabT[3072,1024]^T; each wave owns a 64x64
// sub-tile = exactly one 64-wide head group, so LN stats are per-row
// reductions: sum over 4 j-registers + shfl_xor(1,2,4,8) over the 16-lane
// group (lane = kh*16+lm; masks <16 stay within kh group).
// ---------------------------------------------------------------------------
__global__ __launch_bounds__(256) void ha_gemm_qab(
    const short* __restrict__ Ab, const short* __restrict__ Bt,
    short* __restrict__ q, short* __restrict__ a, short* __restrict__ bOut,
    const float* __restrict__ qg, const float* __restrict__ qbet,
    const float* __restrict__ ag, const float* __restrict__ abet,
    const float* __restrict__ bg, const float* __restrict__ bbet) {
  __shared__ short As[128 * 32] __attribute__((aligned(16)));
  __shared__ short Bs[128 * 32] __attribute__((aligned(16)));
  const int tid = threadIdx.x;
  const int wave = tid >> 6, lane = tid & 63;
  const int m0  = blockIdx.y * 128;
  const int n0g = blockIdx.x * 128;           // [0, 3072)
  short* Cbuf; const float* gamma; const float* beta;
  if (n0g < 1024)      { Cbuf = q;    gamma = qg; beta = qbet; }
  else if (n0g < 2048) { Cbuf = a;    gamma = ag; beta = abet; }
  else                 { Cbuf = bOut; gamma = bg; beta = bbet; }
  const int n0 = n0g & 1023;

  const int srow = wave * 32 + (lane >> 2);
  const int scol = (lane & 3) * 8;
  const short* agp = Ab + (size_t)(m0 + srow) * DMODEL + scol;
  const short* bgp = Bt + (size_t)(n0g + srow) * DMODEL + scol;
  short* alp = As + wave * 32 * 32;
  short* blp = Bs + wave * 32 * 32;

  f32x4 acc[4][4] = {};
  const int lm = lane & 15, kh = lane >> 4;
  const int wm = (wave >> 1) * 64, wn = (wave & 1) * 64;

  float gl[4], bl[4];
  #pragma unroll
  for (int j = 0; j < 4; ++j) {
    gl[j] = gamma[j * 16 + lm];
    bl[j] = beta[j * 16 + lm];
  }

  for (int k0 = 0; k0 < DMODEL; k0 += 32) {
    GLDS(agp,               alp);
    GLDS(agp + 16 * DMODEL, alp + 16 * 32);
    GLDS(bgp,               blp);
    GLDS(bgp + 16 * DMODEL, blp + 16 * 32);
    agp += 32; bgp += 32;
    __syncthreads();
    short8 af[4], bf[4];
    #pragma unroll
    for (int i = 0; i < 4; ++i) {
      af[i] = *(const short8*)&As[(wm + i * 16 + lm) * 32 + kh * 8];
      bf[i] = *(const short8*)&Bs[(wn + i * 16 + lm) * 32 + kh * 8];
    }
    #pragma unroll
    for (int i = 0; i < 4; ++i)
      #pragma unroll
      for (int j = 0; j < 4; ++j)
        acc[i][j] = __builtin_amdgcn_mfma_f32_16x16x32_bf16(
            af[i], bf[j], acc[i][j], 0, 0, 0);
    __syncthreads();
  }

  // ---- fused LayerNorm epilogue (per output row within the head group) ----
  #pragma unroll
  for (int i = 0; i < 4; ++i) {
    float s1[4] = {0.f, 0.f, 0.f, 0.f};
    float s2[4] = {0.f, 0.f, 0.f, 0.f};
    #pragma unroll
    for (int j = 0; j < 4; ++j)
      #pragma unroll
      for (int r = 0; r < 4; ++r) {
        const float v = acc[i][j][r];
        s1[r] += v; s2[r] += v * v;
      }
    #pragma unroll
    for (int m = 1; m <= 8; m <<= 1)
      #pragma unroll
      for (int r = 0; r < 4; ++r) {
        s1[r] += __shfl_xor(s1[r], m);
        s2[r] += __shfl_xor(s2[r], m);
      }
    #pragma unroll
    for (int r = 0; r < 4; ++r) {
      const float mean = s1[r] * 0.015625f;
      const float var  = s2[r] * 0.015625f - mean * mean;
      const float rs   = rsqrtf(var + 1e-5f);
      short* cp = Cbuf + (size_t)(m0 + wm + i * 16 + kh * 4 + r) * DMODEL +
                  n0 + wn + lm;
      #pragma unroll
      for (int j = 0; j < 4; ++j)
        cp[j * 16] = (short)f2bf((acc[i][j][r] - mean) * rs * gl[j] + bl[j]);
    }
  }
}

// ---------------------------------------------------------------------------
// Output GEMM: C[M,1024] = Ob[M,1024](bf16) @ WoT[1024,1024]^T
// ---------------------------------------------------------------------------
__global__ __launch_bounds__(256) void ha_gemm_out(
    const short* __restrict__ Ab, const short* __restrict__ Bt,
    float* __restrict__ C) {
  __shared__ short As[128 * 32] __attribute__((aligned(16)));
  __shared__ short Bs[64 * 32] __attribute__((aligned(16)));
  const int tid = threadIdx.x;
  const int wave = tid >> 6, lane = tid & 63;
  const int m0 = blockIdx.y * 128;
  const int n0 = blockIdx.x * 64;

  const int arow = wave * 32 + (lane >> 2);
  const int brow = wave * 16 + (lane >> 2);
  const int scol = (lane & 3) * 8;
  const short* agp = Ab + (size_t)(m0 + arow) * DMODEL + scol;
  const short* bgp = Bt + (size_t)(n0 + brow) * DMODEL + scol;
  short* alp = As + wave * 32 * 32;
  short* blp = Bs + wave * 16 * 32;

  f32x4 acc[4][2] = {};
  const int lm = lane & 15, kh = lane >> 4;
  const int wm = (wave >> 1) * 64, wn = (wave & 1) * 32;

  for (int k0 = 0; k0 < DMODEL; k0 += 32) {
    GLDS(agp,               alp);
    GLDS(agp + 16 * DMODEL, alp + 16 * 32);
    GLDS(bgp,               blp);
    agp += 32; bgp += 32;
    __syncthreads();
    short8 af[4], bf2[2];
    #pragma unroll
    for (int i = 0; i < 4; ++i)
      af[i] = *(const short8*)&As[(wm + i * 16 + lm) * 32 + kh * 8];
    #pragma unroll
    for (int j = 0; j < 2; ++j)
      bf2[j] = *(const short8*)&Bs[(wn + j * 16 + lm) * 32 + kh * 8];
    #pragma unroll
    for (int i = 0; i < 4; ++i)
      #pragma unroll
      for (int j = 0; j < 2; ++j)
        acc[i][j] = __builtin_amdgcn_mfma_f32_16x16x32_bf16(
            af[i], bf2[j], acc[i][j], 0, 0, 0);
    __syncthreads();
  }
  #pragma unroll
  for (int i = 0; i < 4; ++i)
    #pragma unroll
    for (int j = 0; j < 2; ++j) {
      float* cp = C + (size_t)(m0 + wm + i * 16 + kh * 4) * DMODEL +
                  n0 + wn + j * 16 + lm;
      #pragma unroll
      for (int r = 0; r < 4; ++r) cp[(size_t)r * DMODEL] = acc[i][j][r];
    }
}

// ---------------------------------------------------------------------------
// Scan pass 1: bf16 inputs, fp32 compute. Per (bh, chunk):
//   Asum, Bsum, Mlocal[e][d] = sum_s b_s (x) laexcl_s
// ---------------------------------------------------------------------------
__global__ __launch_bounds__(256) void ha_scan1(
    const short* __restrict__ An, const short* __restrict__ Bn,
    float* __restrict__ M, float* __restrict__ Asums, float* __restrict__ Bsums) {
  __shared__ float Al[64][68];
  __shared__ float Bl[64][68];
  __shared__ float sega[4][64];
  __shared__ float segb[4][64];
  const int bid = blockIdx.x;
  const int c   = bid & (N_CHK - 1);
  const int bh  = bid >> 5;
  const int b = bh >> 4, h = bh & 15;
  const int tid = threadIdx.x;
  const size_t rowbase = ((size_t)b * T_LEN + (size_t)c * L_CHK) * DMODEL + h * HDIM;

  #pragma unroll
  for (int i = 0; i < 2; ++i) {
    const int idx = tid + 256 * i;
    const int s = idx >> 3, c8 = (idx & 7) * 8;
    short8 a8 = *(const short8*)(An + rowbase + (size_t)s * DMODEL + c8);
    short8 b8 = *(const short8*)(Bn + rowbase + (size_t)s * DMODEL + c8);
    #pragma unroll
    for (int k = 0; k < 8; ++k) {
      Al[s][c8 + k] = bf2f(a8[k]);
      Bl[s][c8 + k] = bf2f(b8[k]);
    }
  }
  __syncthreads();

  const int d = tid & 63, seg = tid >> 6;
  {
    float run = 0.f, runb = 0.f;
    for (int s = seg * 16; s < seg * 16 + 16; ++s) {
      const float va = Al[s][d];
      Al[s][d] = run;
      run  += va;
      runb += Bl[s][d];
    }
    sega[seg][d] = run;
    segb[seg][d] = runb;
  }
  __syncthreads();
  {
    float off = 0.f;
    for (int qq = 0; qq < seg; ++qq) off += sega[qq][d];
    for (int s = seg * 16; s < seg * 16 + 16; ++s) Al[s][d] += off;
    if (seg == 0) {
      Asums[((size_t)bh * N_CHK + c) * 64 + d] =
          sega[0][d] + sega[1][d] + sega[2][d] + sega[3][d];
      Bsums[((size_t)bh * N_CHK + c) * 64 + d] =
          segb[0][d] + segb[1][d] + segb[2][d] + segb[3][d];
    }
  }
  __syncthreads();

  const int e0 = (tid >> 4) * 4, d0 = (tid & 15) * 4;
  float acc[4][4];
  #pragma unroll
  for (int i = 0; i < 4; ++i)
    #pragma unroll
    for (int j = 0; j < 4; ++j) acc[i][j] = 0.f;
  #pragma unroll 8
  for (int s = 0; s < 64; ++s) {
    const float4 bv = *(const float4*)&Bl[s][e0];
    const float4 av = *(const float4*)&Al[s][d0];
    const float bb_[4] = {bv.x, bv.y, bv.z, bv.w};
    const float aa_[4] = {av.x, av.y, av.z, av.w};
    #pragma unroll
    for (int i = 0; i < 4; ++i)
      #pragma unroll
      for (int j = 0; j < 4; ++j) acc[i][j] = fmaf(bb_[i], aa_[j], acc[i][j]);
  }
  float* Mp = M + ((size_t)bh * N_CHK + c) * 4096;
  #pragma unroll
  for (int i = 0; i < 4; ++i)
    *(float4*)(Mp + (e0 + i) * 64 + d0) =
        make_float4(acc[i][0], acc[i][1], acc[i][2], acc[i][3]);
}

// ---------------------------------------------------------------------------
// Aoff prefix: Asums[bh][c][d] -> exclusive prefix over c (in place).
// grid = BH (32), 64 threads.
// ---------------------------------------------------------------------------
__global__ __launch_bounds__(64) void ha_aoff(float* __restrict__ Asums) {
  const int bh = blockIdx.x, d = threadIdx.x;
  float run = 0.f;
  for (int c = 0; c < N_CHK; ++c) {
    const size_t off = ((size_t)bh * N_CHK + c) * 64 + d;
    const float v = Asums[off];
    Asums[off] = run;
    run += v;
  }
}

// ---------------------------------------------------------------------------
// Parallel S-prefix: M[bh][c] -> Soff (exclusive prefix of Bsum (x) Aoff + M).
// grid = BH*8 = 256 blocks, 256 threads; block owns 8 e-rows across all c.
// ---------------------------------------------------------------------------
__global__ __launch_bounds__(256) void ha_s2p(
    float* __restrict__ M, const float* __restrict__ Aoff,
    const float* __restrict__ Bsums) {
  const int part = blockIdx.x & 7;
  const int bh   = blockIdx.x >> 3;
  const int tid  = threadIdx.x;
  const int e = part * 8 + (tid >> 5);
  const int d = (tid & 31) * 2;
  float2 S = make_float2(0.f, 0.f);
  for (int c = 0; c < N_CHK; ++c) {
    const size_t vec = ((size_t)bh * N_CHK + c) * 64;
    const float bs = Bsums[vec + e];
    const float2 ao = *(const float2*)&Aoff[vec + d];
    float* Mp = M + ((size_t)bh * N_CHK + c) * 4096 + e * 64 + d;
    const float2 m = *(const float2*)Mp;
    *(float2*)Mp = S;
    S.x += fmaf(bs, ao.x, m.x);
    S.y += fmaf(bs, ao.y, m.y);
  }
}

// ---------------------------------------------------------------------------
// Scan pass 3: bf16 q/a/b in, bf16 O out; fp32 compute (unchanged dataflow).
// ---------------------------------------------------------------------------
__global__ __launch_bounds__(256) void ha_scan3(
    const short* __restrict__ Qn, const short* __restrict__ An,
    const short* __restrict__ Bn, const float* __restrict__ Soff,
    const float* __restrict__ Aoff, short* __restrict__ Ob) {
  __shared__ float Qt[64][68];
  __shared__ float Gt[64][68];
  __shared__ float Bl[64][68];
  __shared__ float Pt[64][68];
  const int bid = blockIdx.x;
  const int c   = bid & (N_CHK - 1);
  const int bh  = bid >> 5;
  const int b = bh >> 4, h = bh & 15;
  const int tid = threadIdx.x;
  const size_t rowbase = ((size_t)b * T_LEN + (size_t)c * L_CHK) * DMODEL + h * HDIM;

  #pragma unroll
  for (int i = 0; i < 2; ++i) {
    const int idx = tid + 256 * i;
    const int t = idx >> 3, c8 = (idx & 7) * 8;
    short8 q8 = *(const short8*)(Qn + rowbase + (size_t)t * DMODEL + c8);
    short8 a8 = *(const short8*)(An + rowbase + (size_t)t * DMODEL + c8);
    short8 b8 = *(const short8*)(Bn + rowbase + (size_t)t * DMODEL + c8);
    #pragma unroll
    for (int k = 0; k < 8; ++k) {
      Qt[c8 + k][t] = bf2f(q8[k]);
      Gt[c8 + k][t] = bf2f(a8[k]);
      Bl[t][c8 + k] = bf2f(b8[k]);
    }
  }
  __syncthreads();

  if (tid < 64) {
    float run = Aoff[((size_t)bh * N_CHK + c) * 64 + tid];
    for (int s = 0; s < 64; ++s) {
      const float v = Gt[tid][s];
      Gt[tid][s] = run;
      run += v;
    }
  }
  __syncthreads();

  const int tt = tid >> 4, ss = tid & 15;
  const int t0 = tt * 4, s0 = ss * 4;
  {
    float p[4][4];
    #pragma unroll
    for (int i = 0; i < 4; ++i)
      #pragma unroll
      for (int j = 0; j < 4; ++j) p[i][j] = 0.f;
    #pragma unroll 8
    for (int k = 0; k < 64; ++k) {
      const float4 qv = *(const float4*)&Qt[k][t0];
      const float4 gv = *(const float4*)&Gt[k][s0];
      const float qq[4] = {qv.x, qv.y, qv.z, qv.w};
      const float gg[4] = {gv.x, gv.y, gv.z, gv.w};
      #pragma unroll
      for (int i = 0; i < 4; ++i)
        #pragma unroll
        for (int j = 0; j < 4; ++j) p[i][j] = fmaf(qq[i], gg[j], p[i][j]);
    }
    #pragma unroll
    for (int i = 0; i < 4; ++i)
      #pragma unroll
      for (int j = 0; j < 4; ++j)
        Pt[s0 + j][t0 + i] = (s0 + j <= t0 + i) ? p[i][j] : 0.f;
  }
  __syncthreads();

  const float* Sg = Soff + ((size_t)bh * N_CHK + c) * 4096;
  #pragma unroll
  for (int i = 0; i < 4; ++i) {
    const int idx = tid + 256 * i;
    const int e = idx >> 4, d4 = idx & 15;
    float4 s4 = *(const float4*)(Sg + (size_t)e * 64 + d4 * 4);
    Gt[d4 * 4 + 0][e] = s4.x; Gt[d4 * 4 + 1][e] = s4.y;
    Gt[d4 * 4 + 2][e] = s4.z; Gt[d4 * 4 + 3][e] = s4.w;
  }
  __syncthreads();

  const int e0 = s0;
  float o[4][4];
  #pragma unroll
  for (int i = 0; i < 4; ++i)
    #pragma unroll
    for (int j = 0; j < 4; ++j) o[i][j] = 0.f;
  #pragma unroll 8
  for (int s = 0; s < 64; ++s) {
    const float4 pv = *(const float4*)&Pt[s][t0];
    const float4 bv = *(const float4*)&Bl[s][e0];
    const float pp[4] = {pv.x, pv.y, pv.z, pv.w};
    const float bb_[4] = {bv.x, bv.y, bv.z, bv.w};
    #pragma unroll
    for (int i = 0; i < 4; ++i)
      #pragma unroll
      for (int j = 0; j < 4; ++j) o[i][j] = fmaf(pp[i], bb_[j], o[i][j]);
  }
  #pragma unroll 8
  for (int dd = 0; dd < 64; ++dd) {
    const float4 qv = *(const float4*)&Qt[dd][t0];
    const float4 sv = *(const float4*)&Gt[dd][e0];
    const float qq[4] = {qv.x, qv.y, qv.z, qv.w};
    const float sS[4] = {sv.x, sv.y, sv.z, sv.w};
    #pragma unroll
    for (int i = 0; i < 4; ++i)
      #pragma unroll
      for (int j = 0; j < 4; ++j) o[i][j] = fmaf(qq[i], sS[j], o[i][j]);
  }
  #pragma unroll
  for (int i = 0; i < 4; ++i) {
    ushort4v o4 = { f2bf(o[i][0]), f2bf(o[i][1]), f2bf(o[i][2]), f2bf(o[i][3]) };
    *(ushort4v*)(Ob + rowbase + (size_t)(t0 + i) * DMODEL + e0) = o4;
  }
}

// ---------------------------------------------------------------------------
extern "C" void kernel_launch(void* const* d_in, const int* in_sizes, int n_in,
                              void* d_out, int out_size, void* d_ws,
                              size_t ws_size, hipStream_t stream) {
  const float* x  = (const float*)d_in[0];
  const float* Wq = (const float*)d_in[1];
  const float* Wa = (const float*)d_in[2];
  const float* Wb = (const float*)d_in[3];
  const float* Wo = (const float*)d_in[4];
  const float* qg = (const float*)d_in[5];
  const float* qb = (const float*)d_in[6];
  const float* ag = (const float*)d_in[7];
  const float* ab = (const float*)d_in[8];
  const float* bg = (const float*)d_in[9];
  const float* bb = (const float*)d_in[10];
  float* out = (float*)d_out;

  // workspace layout (~41 MB of the 64 MB proven available):
  char* ws = (char*)d_ws;
  short* qn  = (short*)(ws);                          // [0,8) MB bf16
  short* an  = (short*)(ws + ((size_t)8  << 20));     // [8,16) MB
  short* bn  = (short*)(ws + ((size_t)16 << 20));     // [16,24) MB
  short* xb  = (short*)(ws + ((size_t)24 << 20));     // [24,32) MB
  short* obb = xb;                                    // overlay: xb dead after QAB GEMM
  short* wqabT = (short*)(ws + ((size_t)32 << 20));   // [32,38) MB
  short* woT   = (short*)(ws + ((size_t)38 << 20));   // [38,40) MB
  float* asums = (float*)(ws + ((size_t)40 << 20));   // 256 KB
  float* bsums = asums + (size_t)BH * N_CHK * 64;     // 256 KB
  float* Mbuf  = out;   // d_out doubles as Mlocal/Soff scratch (16 MB exactly)

  ha_convx<<<(MROWS * DMODEL) / (256 * 8), 256, 0, stream>>>(x, xb);
  ha_convT4<<<dim3(16, 16, 4), 256, 0, stream>>>(Wq, Wa, Wb, Wo, wqabT, woT);

  ha_gemm_qab<<<dim3(24, 32), 256, 0, stream>>>(xb, wqabT, qn, an, bn,
                                                qg, qb, ag, ab, bg, bb);

  ha_scan1<<<BH * N_CHK, 256, 0, stream>>>(an, bn, Mbuf, asums, bsums);
  ha_aoff<<<BH, 64, 0, stream>>>(asums);
  ha_s2p<<<BH * 8, 256, 0, stream>>>(Mbuf, asums, bsums);
  ha_scan3<<<BH * N_CHK, 256, 0, stream>>>(qn, an, bn, Mbuf, asums, obb);

  ha_gemm_out<<<dim3(16, 32), 256, 0, stream>>>(obb, woT, out);
}

// Round 6
// 200.499 us; speedup vs baseline: 6.7918x; 1.0232x over previous
//
#include <hip/hip_runtime.h>
#include <hip/hip_bf16.h>

#define T_LEN  2048
#define NHEAD  16
#define HDIM   64
#define DMODEL 1024
#define BATCH  2
#define MROWS  4096   // B*T
#define L_CHK  64
#define N_CHK  (T_LEN / L_CHK)   // 32
#define BH     (BATCH * NHEAD)   // 32

typedef __attribute__((ext_vector_type(8))) short short8;
typedef __attribute__((ext_vector_type(4))) float f32x4;
typedef __attribute__((ext_vector_type(4))) unsigned short ushort4v;

// async global->LDS, 16B per lane; LDS dest = wave-uniform base + lane*16
#define GLDS(GP, LP) __builtin_amdgcn_global_load_lds( \
    (__attribute__((address_space(1))) void*)(void*)(GP), \
    (__attribute__((address_space(3))) void*)(LP), 16, 0, 0)

__device__ __forceinline__ unsigned short f2bf(float f) {
  union { float f; unsigned int u; } v; v.f = f;
  unsigned int r = v.u + 0x7FFFu + ((v.u >> 16) & 1u);   // RNE
  return (unsigned short)(r >> 16);
}
__device__ __forceinline__ float bf2f(short s) {
  union { unsigned int u; float f; } v;
  v.u = ((unsigned int)(unsigned short)s) << 16;
  return v.f;
}

// ---------------------------------------------------------------------------
// Weight transposes + x conversion in one launch: grid (16,16,5).
// z<3 -> wqabT at z*1024 rows; z==3 -> woT; z==4 -> x fp32->bf16.
// ---------------------------------------------------------------------------
__global__ __launch_bounds__(256) void ha_conv(
    const float* __restrict__ Wq, const float* __restrict__ Wa,
    const float* __restrict__ Wb, const float* __restrict__ Wo,
    const float* __restrict__ X,
    short* __restrict__ wqabT, short* __restrict__ woT,
    short* __restrict__ Xb) {
  const int z = blockIdx.z;
  const int tid = threadIdx.x;
  if (z == 4) {   // x conversion: 256 blocks x 16384 floats
    const int bidl = blockIdx.y * 16 + blockIdx.x;
    #pragma unroll
    for (int p = 0; p < 8; ++p) {
      const size_t idx = (size_t)bidl * 16384 + (size_t)p * 2048 + tid * 8;
      float4 v0 = *(const float4*)(X + idx);
      float4 v1 = *(const float4*)(X + idx + 4);
      short8 o;
      o[0] = (short)f2bf(v0.x); o[1] = (short)f2bf(v0.y);
      o[2] = (short)f2bf(v0.z); o[3] = (short)f2bf(v0.w);
      o[4] = (short)f2bf(v1.x); o[5] = (short)f2bf(v1.y);
      o[6] = (short)f2bf(v1.z); o[7] = (short)f2bf(v1.w);
      *(short8*)(Xb + idx) = o;
    }
    return;
  }
  __shared__ float tile[64][65];
  const float* W = (z == 0) ? Wq : (z == 1) ? Wa : (z == 2) ? Wb : Wo;
  short* WT = (z < 3) ? wqabT + (size_t)z * 1024 * DMODEL : woT;
  const int k0 = blockIdx.y * 64, n0 = blockIdx.x * 64;
  #pragma unroll
  for (int p = 0; p < 4; ++p) {
    const int r  = p * 16 + (tid >> 4);
    const int c4 = (tid & 15) * 4;
    float4 v = *(const float4*)(W + (size_t)(k0 + r) * DMODEL + n0 + c4);
    tile[r][c4 + 0] = v.x; tile[r][c4 + 1] = v.y;
    tile[r][c4 + 2] = v.z; tile[r][c4 + 3] = v.w;
  }
  __syncthreads();
  #pragma unroll
  for (int p = 0; p < 4; ++p) {
    const int n = p * 16 + (tid >> 4);
    const int c = (tid & 15) * 4;
    ushort4v o = { f2bf(tile[c + 0][n]), f2bf(tile[c + 1][n]),
                   f2bf(tile[c + 2][n]), f2bf(tile[c + 3][n]) };
    *(ushort4v*)(WT + (size_t)(n0 + n) * DMODEL + k0 + c) = o;
  }
}

// ---------------------------------------------------------------------------
// Fused QAB projection GEMM + per-head LayerNorm epilogue, bf16 out.
// LDS layout XOR-swizzled: physical colgroup = logical ^ ((row>>1)&3).
// Staging applies the inverse permutation on the GLOBAL source column
// (global_load_lds pins lane->LDS offset); fragment reads use
// kh ^ ((lm>>1)&3). Bank starts then cover all 8 groups 2-deep = free.
// ---------------------------------------------------------------------------
__global__ __launch_bounds__(256) void ha_gemm_qab(
    const short* __restrict__ Ab, const short* __restrict__ Bt,
    short* __restrict__ q, short* __restrict__ a, short* __restrict__ bOut,
    const float* __restrict__ qg, const float* __restrict__ qbet,
    const float* __restrict__ ag, const float* __restrict__ abet,
    const float* __restrict__ bg, const float* __restrict__ bbet) {
  __shared__ short As[128 * 32] __attribute__((aligned(16)));
  __shared__ short Bs[128 * 32] __attribute__((aligned(16)));
  const int tid = threadIdx.x;
  const int wave = tid >> 6, lane = tid & 63;
  const int m0  = blockIdx.y * 128;
  const int n0g = blockIdx.x * 128;           // [0, 3072)
  short* Cbuf; const float* gamma; const float* beta;
  if (n0g < 1024)      { Cbuf = q;    gamma = qg; beta = qbet; }
  else if (n0g < 2048) { Cbuf = a;    gamma = ag; beta = abet; }
  else                 { Cbuf = bOut; gamma = bg; beta = bbet; }
  const int n0 = n0g & 1023;

  const int srow = wave * 32 + (lane >> 2);
  const int scol = (((lane & 3) ^ ((lane >> 3) & 3))) * 8;   // swizzled source
  const short* agp = Ab + (size_t)(m0 + srow) * DMODEL + scol;
  const short* bgp = Bt + (size_t)(n0g + srow) * DMODEL + scol;
  short* alp = As + wave * 32 * 32;
  short* blp = Bs + wave * 32 * 32;

  f32x4 acc[4][4] = {};
  const int lm = lane & 15, kh = lane >> 4;
  const int wm = (wave >> 1) * 64, wn = (wave & 1) * 64;
  const int khs = (kh ^ ((lm >> 1) & 3)) * 8;                // swizzled frag col

  float gl[4], bl[4];
  #pragma unroll
  for (int j = 0; j < 4; ++j) {
    gl[j] = gamma[j * 16 + lm];
    bl[j] = beta[j * 16 + lm];
  }

  for (int k0 = 0; k0 < DMODEL; k0 += 32) {
    GLDS(agp,               alp);
    GLDS(agp + 16 * DMODEL, alp + 16 * 32);
    GLDS(bgp,               blp);
    GLDS(bgp + 16 * DMODEL, blp + 16 * 32);
    agp += 32; bgp += 32;
    __syncthreads();
    short8 af[4], bf[4];
    #pragma unroll
    for (int i = 0; i < 4; ++i) {
      af[i] = *(const short8*)&As[(wm + i * 16 + lm) * 32 + khs];
      bf[i] = *(const short8*)&Bs[(wn + i * 16 + lm) * 32 + khs];
    }
    #pragma unroll
    for (int i = 0; i < 4; ++i)
      #pragma unroll
      for (int j = 0; j < 4; ++j)
        acc[i][j] = __builtin_amdgcn_mfma_f32_16x16x32_bf16(
            af[i], bf[j], acc[i][j], 0, 0, 0);
    __syncthreads();
  }

  // ---- fused LayerNorm epilogue (per output row within the head group) ----
  #pragma unroll
  for (int i = 0; i < 4; ++i) {
    float s1[4] = {0.f, 0.f, 0.f, 0.f};
    float s2[4] = {0.f, 0.f, 0.f, 0.f};
    #pragma unroll
    for (int j = 0; j < 4; ++j)
      #pragma unroll
      for (int r = 0; r < 4; ++r) {
        const float v = acc[i][j][r];
        s1[r] += v; s2[r] += v * v;
      }
    #pragma unroll
    for (int m = 1; m <= 8; m <<= 1)
      #pragma unroll
      for (int r = 0; r < 4; ++r) {
        s1[r] += __shfl_xor(s1[r], m);
        s2[r] += __shfl_xor(s2[r], m);
      }
    #pragma unroll
    for (int r = 0; r < 4; ++r) {
      const float mean = s1[r] * 0.015625f;
      const float var  = s2[r] * 0.015625f - mean * mean;
      const float rs   = rsqrtf(var + 1e-5f);
      short* cp = Cbuf + (size_t)(m0 + wm + i * 16 + kh * 4 + r) * DMODEL +
                  n0 + wn + lm;
      #pragma unroll
      for (int j = 0; j < 4; ++j)
        cp[j * 16] = (short)f2bf((acc[i][j][r] - mean) * rs * gl[j] + bl[j]);
    }
  }
}

// ---------------------------------------------------------------------------
// Output GEMM: C[M,1024] = Ob[M,1024](bf16) @ WoT[1024,1024]^T (swizzled LDS)
// ---------------------------------------------------------------------------
__global__ __launch_bounds__(256) void ha_gemm_out(
    const short* __restrict__ Ab, const short* __restrict__ Bt,
    float* __restrict__ C) {
  __shared__ short As[128 * 32] __attribute__((aligned(16)));
  __shared__ short Bs[64 * 32] __attribute__((aligned(16)));
  const int tid = threadIdx.x;
  const int wave = tid >> 6, lane = tid & 63;
  const int m0 = blockIdx.y * 128;
  const int n0 = blockIdx.x * 64;

  const int arow = wave * 32 + (lane >> 2);
  const int brow = wave * 16 + (lane >> 2);
  const int scol = (((lane & 3) ^ ((lane >> 3) & 3))) * 8;   // swizzled source
  const short* agp = Ab + (size_t)(m0 + arow) * DMODEL + scol;
  const short* bgp = Bt + (size_t)(n0 + brow) * DMODEL + scol;
  short* alp = As + wave * 32 * 32;
  short* blp = Bs + wave * 16 * 32;

  f32x4 acc[4][2] = {};
  const int lm = lane & 15, kh = lane >> 4;
  const int wm = (wave >> 1) * 64, wn = (wave & 1) * 32;
  const int khs = (kh ^ ((lm >> 1) & 3)) * 8;                // swizzled frag col

  for (int k0 = 0; k0 < DMODEL; k0 += 32) {
    GLDS(agp,               alp);
    GLDS(agp + 16 * DMODEL, alp + 16 * 32);
    GLDS(bgp,               blp);
    agp += 32; bgp += 32;
    __syncthreads();
    short8 af[4], bf2[2];
    #pragma unroll
    for (int i = 0; i < 4; ++i)
      af[i] = *(const short8*)&As[(wm + i * 16 + lm) * 32 + khs];
    #pragma unroll
    for (int j = 0; j < 2; ++j)
      bf2[j] = *(const short8*)&Bs[(wn + j * 16 + lm) * 32 + khs];
    #pragma unroll
    for (int i = 0; i < 4; ++i)
      #pragma unroll
      for (int j = 0; j < 2; ++j)
        acc[i][j] = __builtin_amdgcn_mfma_f32_16x16x32_bf16(
            af[i], bf2[j], acc[i][j], 0, 0, 0);
    __syncthreads();
  }
  #pragma unroll
  for (int i = 0; i < 4; ++i)
    #pragma unroll
    for (int j = 0; j < 2; ++j) {
      float* cp = C + (size_t)(m0 + wm + i * 16 + kh * 4) * DMODEL +
                  n0 + wn + j * 16 + lm;
      #pragma unroll
      for (int r = 0; r < 4; ++r) cp[(size_t)r * DMODEL] = acc[i][j][r];
    }
}

// ---------------------------------------------------------------------------
// Scan pass 1: bf16 inputs, fp32 compute. Per (bh, chunk):
//   Asum, Bsum, Mlocal[e][d] = sum_s b_s (x) laexcl_s
// ---------------------------------------------------------------------------
__global__ __launch_bounds__(256) void ha_scan1(
    const short* __restrict__ An, const short* __restrict__ Bn,
    float* __restrict__ M, float* __restrict__ Asums, float* __restrict__ Bsums) {
  __shared__ float Al[64][68];
  __shared__ float Bl[64][68];
  __shared__ float sega[4][64];
  __shared__ float segb[4][64];
  const int bid = blockIdx.x;
  const int c   = bid & (N_CHK - 1);
  const int bh  = bid >> 5;
  const int b = bh >> 4, h = bh & 15;
  const int tid = threadIdx.x;
  const size_t rowbase = ((size_t)b * T_LEN + (size_t)c * L_CHK) * DMODEL + h * HDIM;

  #pragma unroll
  for (int i = 0; i < 2; ++i) {
    const int idx = tid + 256 * i;
    const int s = idx >> 3, c8 = (idx & 7) * 8;
    short8 a8 = *(const short8*)(An + rowbase + (size_t)s * DMODEL + c8);
    short8 b8 = *(const short8*)(Bn + rowbase + (size_t)s * DMODEL + c8);
    #pragma unroll
    for (int k = 0; k < 8; ++k) {
      Al[s][c8 + k] = bf2f(a8[k]);
      Bl[s][c8 + k] = bf2f(b8[k]);
    }
  }
  __syncthreads();

  const int d = tid & 63, seg = tid >> 6;
  {
    float run = 0.f, runb = 0.f;
    for (int s = seg * 16; s < seg * 16 + 16; ++s) {
      const float va = Al[s][d];
      Al[s][d] = run;
      run  += va;
      runb += Bl[s][d];
    }
    sega[seg][d] = run;
    segb[seg][d] = runb;
  }
  __syncthreads();
  {
    float off = 0.f;
    for (int qq = 0; qq < seg; ++qq) off += sega[qq][d];
    for (int s = seg * 16; s < seg * 16 + 16; ++s) Al[s][d] += off;
    if (seg == 0) {
      Asums[((size_t)bh * N_CHK + c) * 64 + d] =
          sega[0][d] + sega[1][d] + sega[2][d] + sega[3][d];
      Bsums[((size_t)bh * N_CHK + c) * 64 + d] =
          segb[0][d] + segb[1][d] + segb[2][d] + segb[3][d];
    }
  }
  __syncthreads();

  const int e0 = (tid >> 4) * 4, d0 = (tid & 15) * 4;
  float acc[4][4];
  #pragma unroll
  for (int i = 0; i < 4; ++i)
    #pragma unroll
    for (int j = 0; j < 4; ++j) acc[i][j] = 0.f;
  #pragma unroll 8
  for (int s = 0; s < 64; ++s) {
    const float4 bv = *(const float4*)&Bl[s][e0];
    const float4 av = *(const float4*)&Al[s][d0];
    const float bb_[4] = {bv.x, bv.y, bv.z, bv.w};
    const float aa_[4] = {av.x, av.y, av.z, av.w};
    #pragma unroll
    for (int i = 0; i < 4; ++i)
      #pragma unroll
      for (int j = 0; j < 4; ++j) acc[i][j] = fmaf(bb_[i], aa_[j], acc[i][j]);
  }
  float* Mp = M + ((size_t)bh * N_CHK + c) * 4096;
  #pragma unroll
  for (int i = 0; i < 4; ++i)
    *(float4*)(Mp + (e0 + i) * 64 + d0) =
        make_float4(acc[i][0], acc[i][1], acc[i][2], acc[i][3]);
}

// ---------------------------------------------------------------------------
// Parallel S-prefix (Aoff prefix fused): per block, load Asums[bh] to LDS,
// compute c-prefix locally; part-0 block exports Aoff for scan3; then the
// exclusive S prefix over chunks. grid = BH*8, 256 threads.
// ---------------------------------------------------------------------------
__global__ __launch_bounds__(256) void ha_s2p(
    float* __restrict__ M, const float* __restrict__ Asums,
    const float* __restrict__ Bsums, float* __restrict__ Aoff) {
  __shared__ float ao[N_CHK][64];   // 8 KB
  const int part = blockIdx.x & 7;
  const int bh   = blockIdx.x >> 3;
  const int tid  = threadIdx.x;
  for (int i = tid; i < N_CHK * 64; i += 256)
    ao[i >> 6][i & 63] = Asums[(size_t)bh * N_CHK * 64 + i];
  __syncthreads();
  if (tid < 64) {
    float run = 0.f;
    for (int c = 0; c < N_CHK; ++c) {
      const float v = ao[c][tid];
      ao[c][tid] = run;
      run += v;
    }
  }
  __syncthreads();
  if (part == 0)
    for (int i = tid; i < N_CHK * 64; i += 256)
      Aoff[(size_t)bh * N_CHK * 64 + i] = ao[i >> 6][i & 63];

  const int e = part * 8 + (tid >> 5);
  const int d = (tid & 31) * 2;
  float2 S = make_float2(0.f, 0.f);
  for (int c = 0; c < N_CHK; ++c) {
    const float bs = Bsums[((size_t)bh * N_CHK + c) * 64 + e];
    const float aox = ao[c][d], aoy = ao[c][d + 1];
    float* Mp = M + ((size_t)bh * N_CHK + c) * 4096 + e * 64 + d;
    const float2 m = *(const float2*)Mp;
    *(float2*)Mp = S;
    S.x += fmaf(bs, aox, m.x);
    S.y += fmaf(bs, aoy, m.y);
  }
}

// ---------------------------------------------------------------------------
// Scan pass 3: bf16 q/a/b in, bf16 O out; fp32 compute.
// ---------------------------------------------------------------------------
__global__ __launch_bounds__(256) void ha_scan3(
    const short* __restrict__ Qn, const short* __restrict__ An,
    const short* __restrict__ Bn, const float* __restrict__ Soff,
    const float* __restrict__ Aoff, short* __restrict__ Ob) {
  __shared__ float Qt[64][68];
  __shared__ float Gt[64][68];
  __shared__ float Bl[64][68];
  __shared__ float Pt[64][68];
  const int bid = blockIdx.x;
  const int c   = bid & (N_CHK - 1);
  const int bh  = bid >> 5;
  const int b = bh >> 4, h = bh & 15;
  const int tid = threadIdx.x;
  const size_t rowbase = ((size_t)b * T_LEN + (size_t)c * L_CHK) * DMODEL + h * HDIM;

  #pragma unroll
  for (int i = 0; i < 2; ++i) {
    const int idx = tid + 256 * i;
    const int t = idx >> 3, c8 = (idx & 7) * 8;
    short8 q8 = *(const short8*)(Qn + rowbase + (size_t)t * DMODEL + c8);
    short8 a8 = *(const short8*)(An + rowbase + (size_t)t * DMODEL + c8);
    short8 b8 = *(const short8*)(Bn + rowbase + (size_t)t * DMODEL + c8);
    #pragma unroll
    for (int k = 0; k < 8; ++k) {
      Qt[c8 + k][t] = bf2f(q8[k]);
      Gt[c8 + k][t] = bf2f(a8[k]);
      Bl[t][c8 + k] = bf2f(b8[k]);
    }
  }
  __syncthreads();

  if (tid < 64) {
    float run = Aoff[((size_t)bh * N_CHK + c) * 64 + tid];
    for (int s = 0; s < 64; ++s) {
      const float v = Gt[tid][s];
      Gt[tid][s] = run;
      run += v;
    }
  }
  __syncthreads();

  const int tt = tid >> 4, ss = tid & 15;
  const int t0 = tt * 4, s0 = ss * 4;
  {
    float p[4][4];
    #pragma unroll
    for (int i = 0; i < 4; ++i)
      #pragma unroll
      for (int j = 0; j < 4; ++j) p[i][j] = 0.f;
    #pragma unroll 8
    for (int k = 0; k < 64; ++k) {
      const float4 qv = *(const float4*)&Qt[k][t0];
      const float4 gv = *(const float4*)&Gt[k][s0];
      const float qq[4] = {qv.x, qv.y, qv.z, qv.w};
      const float gg[4] = {gv.x, gv.y, gv.z, gv.w};
      #pragma unroll
      for (int i = 0; i < 4; ++i)
        #pragma unroll
        for (int j = 0; j < 4; ++j) p[i][j] = fmaf(qq[i], gg[j], p[i][j]);
    }
    #pragma unroll
    for (int i = 0; i < 4; ++i)
      #pragma unroll
      for (int j = 0; j < 4; ++j)
        Pt[s0 + j][t0 + i] = (s0 + j <= t0 + i) ? p[i][j] : 0.f;
  }
  __syncthreads();

  const float* Sg = Soff + ((size_t)bh * N_CHK + c) * 4096;
  #pragma unroll
  for (int i = 0; i < 4; ++i) {
    const int idx = tid + 256 * i;
    const int e = idx >> 4, d4 = idx & 15;
    float4 s4 = *(const float4*)(Sg + (size_t)e * 64 + d4 * 4);
    Gt[d4 * 4 + 0][e] = s4.x; Gt[d4 * 4 + 1][e] = s4.y;
    Gt[d4 * 4 + 2][e] = s4.z; Gt[d4 * 4 + 3][e] = s4.w;
  }
  __syncthreads();

  const int e0 = s0;
  float o[4][4];
  #pragma unroll
  for (int i = 0; i < 4; ++i)
    #pragma unroll
    for (int j = 0; j < 4; ++j) o[i][j] = 0.f;
  #pragma unroll 8
  for (int s = 0; s < 64; ++s) {
    const float4 pv = *(const float4*)&Pt[s][t0];
    const float4 bv = *(const float4*)&Bl[s][e0];
    const float pp[4] = {pv.x, pv.y, pv.z, pv.w};
    const float bb_[4] = {bv.x, bv.y, bv.z, bv.w};
    #pragma unroll
    for (int i = 0; i < 4; ++i)
      #pragma unroll
      for (int j = 0; j < 4; ++j) o[i][j] = fmaf(pp[i], bb_[j], o[i][j]);
  }
  #pragma unroll 8
  for (int dd = 0; dd < 64; ++dd) {
    const float4 qv = *(const float4*)&Qt[dd][t0];
    const float4 sv = *(const float4*)&Gt[dd][e0];
    const float qq[4] = {qv.x, qv.y, qv.z, qv.w};
    const float sS[4] = {sv.x, sv.y, sv.z, sv.w};
    #pragma unroll
    for (int i = 0; i < 4; ++i)
      #pragma unroll
      for (int j = 0; j < 4; ++j) o[i][j] = fmaf(qq[i], sS[j], o[i][j]);
  }
  #pragma unroll
  for (int i = 0; i < 4; ++i) {
    ushort4v o4 = { f2bf(o[i][0]), f2bf(o[i][1]), f2bf(o[i][2]), f2bf(o[i][3]) };
    *(ushort4v*)(Ob + rowbase + (size_t)(t0 + i) * DMODEL + e0) = o4;
  }
}

// ---------------------------------------------------------------------------
extern "C" void kernel_launch(void* const* d_in, const int* in_sizes, int n_in,
                              void* d_out, int out_size, void* d_ws,
                              size_t ws_size, hipStream_t stream) {
  const float* x  = (const float*)d_in[0];
  const float* Wq = (const float*)d_in[1];
  const float* Wa = (const float*)d_in[2];
  const float* Wb = (const float*)d_in[3];
  const float* Wo = (const float*)d_in[4];
  const float* qg = (const float*)d_in[5];
  const float* qb = (const float*)d_in[6];
  const float* ag = (const float*)d_in[7];
  const float* ab = (const float*)d_in[8];
  const float* bg = (const float*)d_in[9];
  const float* bb = (const float*)d_in[10];
  float* out = (float*)d_out;

  // workspace layout (~41 MB of the 64 MB proven available):
  char* ws = (char*)d_ws;
  short* qn  = (short*)(ws);                          // [0,8) MB bf16
  short* an  = (short*)(ws + ((size_t)8  << 20));     // [8,16) MB
  short* bn  = (short*)(ws + ((size_t)16 << 20));     // [16,24) MB
  short* xb  = (short*)(ws + ((size_t)24 << 20));     // [24,32) MB
  short* obb = xb;                                    // overlay: xb dead after QAB GEMM
  short* wqabT = (short*)(ws + ((size_t)32 << 20));   // [32,38) MB
  short* woT   = (short*)(ws + ((size_t)38 << 20));   // [38,40) MB
  float* asums = (float*)(ws + ((size_t)40 << 20));   // 256 KB
  float* bsums = asums + (size_t)BH * N_CHK * 64;     // 256 KB
  float* aoff  = bsums + (size_t)BH * N_CHK * 64;     // 256 KB
  float* Mbuf  = out;   // d_out doubles as Mlocal/Soff scratch (16 MB exactly)

  ha_conv<<<dim3(16, 16, 5), 256, 0, stream>>>(Wq, Wa, Wb, Wo, x,
                                               wqabT, woT, xb);

  ha_gemm_qab<<<dim3(24, 32), 256, 0, stream>>>(xb, wqabT, qn, an, bn,
                                                qg, qb, ag, ab, bg, bb);

  ha_scan1<<<BH * N_CHK, 256, 0, stream>>>(an, bn, Mbuf, asums, bsums);
  ha_s2p<<<BH * 8, 256, 0, stream>>>(Mbuf, asums, bsums, aoff);
  ha_scan3<<<BH * N_CHK, 256, 0, stream>>>(qn, an, bn, Mbuf, aoff, obb);

  ha_gemm_out<<<dim3(16, 32), 256, 0, stream>>>(obb, woT, out);
}